// Round 13
// baseline (277.929 us; speedup 1.0000x reference)
//
#include <hip/hip_runtime.h>

#define D_MODEL 2048
#define SEQ     2048
#define NB      2
#define NH      16
#define DH      128
#define MROWS   (NB*SEQ)   /* 4096 */
#define GK      2048       /* K dim of all GEMMs */
#define NT      (GK/64)    /* 32 K-tiles */

typedef __bf16 bf16x8 __attribute__((ext_vector_type(8)));
typedef float  f32x4  __attribute__((ext_vector_type(4)));
typedef unsigned short ushort8 __attribute__((ext_vector_type(8)));
typedef unsigned int   u32x4   __attribute__((ext_vector_type(4)));

__device__ __forceinline__ unsigned short f2bf(float f) {
  unsigned int u = __float_as_uint(f);
  u += 0x7FFFu + ((u >> 16) & 1u);
  return (unsigned short)(u >> 16);
}

__device__ __forceinline__ unsigned int cvtpk_bf16(float lo, float hi) {
  unsigned int r;
  asm("v_cvt_pk_bf16_f32 %0, %1, %2" : "=v"(r) : "v"(lo), "v"(hi));
  return r;
}

__device__ __forceinline__ void gload16(void* lds, const void* g) {
  __builtin_amdgcn_global_load_lds(
      (__attribute__((address_space(1))) void*)(g),
      (__attribute__((address_space(3))) void*)(lds), 16, 0, 0);
}

/* ---- fused cast: blocks 0-4095 = x (fp32->bf16), 4096-12287 = wq|wk|wv|wo */
__global__ __launch_bounds__(256) void cast_all(
    const float* __restrict__ x,
    const float* __restrict__ w0, const float* __restrict__ w1,
    const float* __restrict__ w2, const float* __restrict__ w3,
    unsigned short* __restrict__ xb, unsigned short* __restrict__ wb) {
  int gb = blockIdx.x;
  const float* src;
  unsigned short* dst;
  int i;
  if (gb < 4096) {
    src = x; dst = xb; i = gb * 256 + threadIdx.x;
  } else {
    int g2 = gb - 4096;
    int which = g2 >> 11;
    src = (which == 0) ? w0 : (which == 1) ? w1 : (which == 2) ? w2 : w3;
    dst = wb + (size_t)which * 4194304;
    i = (g2 & 2047) * 256 + threadIdx.x;
  }
  const float4* p = (const float4*)src;
  float4 a = p[2*i], b = p[2*i+1];
  ushort8 o;
  o[0]=f2bf(a.x); o[1]=f2bf(a.y); o[2]=f2bf(a.z); o[3]=f2bf(a.w);
  o[4]=f2bf(b.x); o[5]=f2bf(b.y); o[6]=f2bf(b.z); o[7]=f2bf(b.w);
  ((ushort8*)dst)[i] = o;
}

/* ---------------- QKV GEMM 256x192, BK=64, 8 waves (2Mx4N), wave-tile
   128x48, 2-slot LDS (112KB), stage-all-at-top + counted vmcnt(7) (r12-proven
   ledger), zero-conflict XOR swizzle, bn-major XCD map, grid 512 = 2 exact
   CU-rounds.  NEW (r13): m201-style 4-phase quadrant cadence — per K-tile,
   quadrant (mh,ks) phases of {ds_read frag subtile -> lgkm(0)+sched_barrier
   -> setprio+12 MFMA -> barrier}; B-frags persist across the mh pair.
   No index algebra changed vs r12.                                         */
__global__ __launch_bounds__(512, 2) void gemm192(
    const unsigned short* __restrict__ A,
    const unsigned short* __restrict__ B,
    const float* __restrict__ b0, const float* __restrict__ b1,
    const float* __restrict__ b2,
    unsigned short* __restrict__ qo, unsigned short* __restrict__ ko,
    unsigned short* __restrict__ vo)
{
  __shared__ char lds[2*57344];   /* slot: A 32KB [256][64] + B 24KB [192][64] */

  const int tid  = threadIdx.x;
  const int lane = tid & 63, wid = tid >> 6;
  const int la   = lane & 15, hi = lane >> 4;
  const int wm   = wid >> 2,  wn = wid & 3;

  const int xcd = (int)blockIdx.x & 7, ii = (int)blockIdx.x >> 3;
  const int bm  = ii >> 2;            /* 16 M-tiles, A-panel-sharing adjacent */
  const int bn  = xcd * 4 + (ii & 3); /* 4 B-panels per XCD (~3MB in L2)      */

  const unsigned short* Ab = A + (size_t)(bm*256) * GK;
  const unsigned short* Bb = B + (size_t)(bn*192) * GK;

  f32x4 acc[8][3];
  #pragma unroll
  for (int m = 0; m < 8; m++)
    #pragma unroll
    for (int n = 0; n < 3; n++) acc[m][n] = f32x4{0.f,0.f,0.f,0.f};

#define STG(slot, kt) do {                                                    \
    char* base_ = lds + (slot)*57344;                                         \
    _Pragma("unroll")                                                         \
    for (int j = 0; j < 4; j++) {                                             \
      int idx = j*512 + tid;                                                  \
      int row = idx >> 3;                                                     \
      int c   = (idx & 7) << 4;                                               \
      gload16(base_ + idx*16,                                                 \
              Ab + (size_t)row*GK + (kt)*64 + ((c ^ ((row&7)<<4)) >> 1));     \
    }                                                                         \
    _Pragma("unroll")                                                         \
    for (int j = 0; j < 3; j++) {                                             \
      int idx = j*512 + tid;                                                  \
      int row = idx >> 3;                                                     \
      int c   = (idx & 7) << 4;                                               \
      gload16(base_ + 32768 + idx*16,                                         \
              Bb + (size_t)row*GK + (kt)*64 + ((c ^ ((row&7)<<4)) >> 1));     \
    }                                                                         \
  } while (0)

  STG(0, 0);
  const int xr = (la & 7) << 4;

  #pragma unroll 1
  for (int t = 0; t < NT; ++t) {
    /* stage t+1 into the slot fenced by iter t-1's trailing barrier; wait
       for tile t with t+1's 7 loads left in flight (never drain mid-loop) */
    if (t + 1 < NT) {
      STG((t+1)&1, t+1);
      asm volatile("s_waitcnt vmcnt(7)" ::: "memory");
    } else {
      asm volatile("s_waitcnt vmcnt(0)" ::: "memory");
    }
    __builtin_amdgcn_s_barrier();

    const char* sa  = lds + (t&1)*57344;
    const char* sbp = sa + 32768;

    bf16x8 bfr[3], aq[4];

    /* ---- P1: quadrant (mh0, ks0): B[ks0] + A rows 0-3 ---- */
    #pragma unroll
    for (int n = 0; n < 3; n++)
      bfr[n] = *(const bf16x8*)(sbp + (((wn*48 + n*16 + la)*128 + hi*16) ^ xr));
    #pragma unroll
    for (int m = 0; m < 4; m++)
      aq[m] = *(const bf16x8*)(sa + (((wm*128 + m*16 + la)*128 + hi*16) ^ xr));
    asm volatile("s_waitcnt lgkmcnt(0)" ::: "memory");
    __builtin_amdgcn_sched_barrier(0);
    __builtin_amdgcn_s_setprio(1);
    #pragma unroll
    for (int m = 0; m < 4; m++)
      #pragma unroll
      for (int n = 0; n < 3; n++)
        acc[m][n] = __builtin_amdgcn_mfma_f32_16x16x32_bf16(aq[m], bfr[n], acc[m][n], 0, 0, 0);
    __builtin_amdgcn_s_setprio(0);
    __builtin_amdgcn_s_barrier();

    /* ---- P2: quadrant (mh1, ks0): A rows 4-7 (B persists) ---- */
    #pragma unroll
    for (int m = 0; m < 4; m++)
      aq[m] = *(const bf16x8*)(sa + (((wm*128 + (m+4)*16 + la)*128 + hi*16) ^ xr));
    asm volatile("s_waitcnt lgkmcnt(0)" ::: "memory");
    __builtin_amdgcn_sched_barrier(0);
    __builtin_amdgcn_s_setprio(1);
    #pragma unroll
    for (int m = 0; m < 4; m++)
      #pragma unroll
      for (int n = 0; n < 3; n++)
        acc[m+4][n] = __builtin_amdgcn_mfma_f32_16x16x32_bf16(aq[m], bfr[n], acc[m+4][n], 0, 0, 0);
    __builtin_amdgcn_s_setprio(0);
    __builtin_amdgcn_s_barrier();

    /* ---- P3: quadrant (mh0, ks1): B[ks1] + A rows 0-3 ---- */
    #pragma unroll
    for (int n = 0; n < 3; n++)
      bfr[n] = *(const bf16x8*)(sbp + (((wn*48 + n*16 + la)*128 + 64 + hi*16) ^ xr));
    #pragma unroll
    for (int m = 0; m < 4; m++)
      aq[m] = *(const bf16x8*)(sa + (((wm*128 + m*16 + la)*128 + 64 + hi*16) ^ xr));
    asm volatile("s_waitcnt lgkmcnt(0)" ::: "memory");
    __builtin_amdgcn_sched_barrier(0);
    __builtin_amdgcn_s_setprio(1);
    #pragma unroll
    for (int m = 0; m < 4; m++)
      #pragma unroll
      for (int n = 0; n < 3; n++)
        acc[m][n] = __builtin_amdgcn_mfma_f32_16x16x32_bf16(aq[m], bfr[n], acc[m][n], 0, 0, 0);
    __builtin_amdgcn_s_setprio(0);
    __builtin_amdgcn_s_barrier();

    /* ---- P4: quadrant (mh1, ks1): A rows 4-7 ---- */
    #pragma unroll
    for (int m = 0; m < 4; m++)
      aq[m] = *(const bf16x8*)(sa + (((wm*128 + (m+4)*16 + la)*128 + 64 + hi*16) ^ xr));
    asm volatile("s_waitcnt lgkmcnt(0)" ::: "memory");
    __builtin_amdgcn_sched_barrier(0);
    __builtin_amdgcn_s_setprio(1);
    #pragma unroll
    for (int m = 0; m < 4; m++)
      #pragma unroll
      for (int n = 0; n < 3; n++)
        acc[m+4][n] = __builtin_amdgcn_mfma_f32_16x16x32_bf16(aq[m], bfr[n], acc[m+4][n], 0, 0, 0);
    __builtin_amdgcn_s_setprio(0);
    __builtin_amdgcn_s_barrier();   /* trailing: fence slot reads before restage */
  }
#undef STG

  /* epilogue: mat per n-frag (192-tiles straddle q/k/v boundaries) */
  const int row0 = bm*256 + wm*128;
  const int col0 = bn*192 + wn*48;
  #pragma unroll
  for (int n = 0; n < 3; n++) {
    int col = col0 + n*16 + la;
    int mat = col >> 11;          /* 0=q 1=k 2=v, uniform across the wave */
    int c   = col & 2047;
    int h   = c >> 7, d = c & 127;
    const float* bp = (mat == 0) ? b0 : (mat == 1) ? b1 : b2;
    float bv = bp[c];
    #pragma unroll
    for (int m = 0; m < 8; m++)
      #pragma unroll
      for (int r = 0; r < 4; r++) {
        int row = row0 + m*16 + hi*4 + r;
        int bb  = row >> 11, s = row & (SEQ-1);
        unsigned short val = f2bf(acc[m][n][r] + bv);
        if (mat == 0) {
          qo[((size_t)(bb*NH + h)*SEQ + s)*DH + d] = val;
        } else if (mat == 1) {
          size_t base = ((size_t)(bb*NH + h)*SEQ + (size_t)(s >> 6)*64)*DH;
          int boff = (((s & 63) << 8) + (d << 1)) ^ ((s & 7) << 4);
          ko[base + (boff >> 1)] = val;
        } else {
          size_t base = ((size_t)(bb*NH + h)*SEQ + (size_t)(s >> 6)*64)*DH;
          int boff = ((d << 7) + ((s & 63) << 1)) ^ ((d & 7) << 4);
          vo[base + (boff >> 1)] = val;
        }
      }
  }
}

/* ---------------- out-proj GEMM 128x256 (round-6 proven, mode-1 use) ---- */
__global__ __launch_bounds__(512, 2) void gemm256(
    const unsigned short* __restrict__ A,
    const unsigned short* __restrict__ B,
    const float* __restrict__ b0,
    float* __restrict__ fo,
    int nbnx)
{
  __shared__ char lds[3*49152];

  const int tid  = threadIdx.x;
  const int lane = tid & 63, wid = tid >> 6;
  const int la   = lane & 15, hi = lane >> 4;
  const int wm   = wid >> 2,  wn = wid & 3;

  const int xcd = (int)blockIdx.x & 7, ii = (int)blockIdx.x >> 3;
  const int bm  = ii / nbnx;
  const int bn  = xcd * nbnx + ii % nbnx;

  const unsigned short* Ab = A + (size_t)(bm*128) * GK;
  const unsigned short* Bb = B + (size_t)(bn*256) * GK;

  f32x4 acc[4][4];
  #pragma unroll
  for (int m = 0; m < 4; m++)
    #pragma unroll
    for (int n = 0; n < 4; n++) acc[m][n] = f32x4{0.f,0.f,0.f,0.f};

#define STAGE_A(slot, kt) do {                                                \
    int sb_ = (slot) * 49152;                                                 \
    _Pragma("unroll")                                                         \
    for (int j = 0; j < 2; j++) {                                             \
      int idx = j*512 + tid;                                                  \
      int row = idx >> 3;                                                     \
      int c   = (idx & 7) << 4;                                               \
      gload16(lds + sb_ + idx*16,                                             \
              Ab + (size_t)row*GK + (kt)*64 + ((c ^ ((row&7)<<4)) >> 1));     \
    }                                                                         \
  } while (0)

#define STAGE_B(slot, kt) do {                                                \
    int sb_ = (slot) * 49152;                                                 \
    _Pragma("unroll")                                                         \
    for (int j = 0; j < 4; j++) {                                             \
      int idx = j*512 + tid;                                                  \
      int row = idx >> 3;                                                     \
      int c   = (idx & 7) << 4;                                               \
      gload16(lds + sb_ + 16384 + idx*16,                                     \
              Bb + (size_t)row*GK + (kt)*64 + ((c ^ ((row&7)<<4)) >> 1));     \
    }                                                                         \
  } while (0)

  STAGE_A(0, 0); STAGE_B(0, 0);
  STAGE_A(1, 1); STAGE_B(1, 1);

  int cs = 0, ps = 2;
  const int xr = (la & 7) << 4;

  #pragma unroll 1
  for (int t = 0; t < NT; ++t) {
    if (t + 1 < NT) asm volatile("s_waitcnt vmcnt(6)" ::: "memory");
    else            asm volatile("s_waitcnt vmcnt(0)" ::: "memory");
    __builtin_amdgcn_s_barrier();

    const char* sa  = lds + cs*49152;
    const char* sbp = sa + 16384;

    bf16x8 bfr[4][2], aA[2][2];
    #pragma unroll
    for (int n = 0; n < 4; n++)
      #pragma unroll
      for (int ks = 0; ks < 2; ks++)
        bfr[n][ks] = *(const bf16x8*)(sbp + (((wn*64 + n*16 + la)*128 + ks*64 + hi*16) ^ xr));
    #pragma unroll
    for (int m = 0; m < 2; m++)
      #pragma unroll
      for (int ks = 0; ks < 2; ks++)
        aA[m][ks] = *(const bf16x8*)(sa + (((wm*64 + m*16 + la)*128 + ks*64 + hi*16) ^ xr));

    if (t + 2 < NT) STAGE_A(ps, t + 2);

    asm volatile("s_waitcnt lgkmcnt(0)" ::: "memory");
    __builtin_amdgcn_sched_barrier(0);
    __builtin_amdgcn_s_setprio(1);
    #pragma unroll
    for (int m = 0; m < 2; m++)
      #pragma unroll
      for (int n = 0; n < 4; n++)
        #pragma unroll
        for (int ks = 0; ks < 2; ks++)
          acc[m][n] = __builtin_amdgcn_mfma_f32_16x16x32_bf16(aA[m][ks], bfr[n][ks], acc[m][n], 0, 0, 0);
    __builtin_amdgcn_s_setprio(0);
    __builtin_amdgcn_s_barrier();

    bf16x8 aB[2][2];
    #pragma unroll
    for (int m = 0; m < 2; m++)
      #pragma unroll
      for (int ks = 0; ks < 2; ks++)
        aB[m][ks] = *(const bf16x8*)(sa + (((wm*64 + (m+2)*16 + la)*128 + ks*64 + hi*16) ^ xr));

    if (t + 2 < NT) STAGE_B(ps, t + 2);

    asm volatile("s_waitcnt lgkmcnt(0)" ::: "memory");
    __builtin_amdgcn_sched_barrier(0);
    __builtin_amdgcn_s_setprio(1);
    #pragma unroll
    for (int m = 0; m < 2; m++)
      #pragma unroll
      for (int n = 0; n < 4; n++)
        #pragma unroll
        for (int ks = 0; ks < 2; ks++)
          acc[m+2][n] = __builtin_amdgcn_mfma_f32_16x16x32_bf16(aB[m][ks], bfr[n][ks], acc[m+2][n], 0, 0, 0);
    __builtin_amdgcn_s_setprio(0);

    cs = cs + 1; if (cs == 3) cs = 0;
    ps = ps + 1; if (ps == 3) ps = 0;
  }
#undef STAGE_A
#undef STAGE_B

  const int row0 = bm*128 + wm*64;
  const int col0 = bn*256 + wn*64;
  #pragma unroll
  for (int n = 0; n < 4; n++) {
    int col = col0 + n*16 + la;
    float bv = b0[col];
    #pragma unroll
    for (int m = 0; m < 4; m++)
      #pragma unroll
      for (int r = 0; r < 4; r++) {
        int row = row0 + m*16 + hi*4 + r;
        fo[(size_t)row*D_MODEL + col] = acc[m][n][r] + bv;
      }
  }
}

/* ---------------- flash attention fwd (round-10 proven: T13 defer-max +
   exp2-domain softmax) ---------------- */
__global__ __launch_bounds__(256, 2) void attn_fwd(
    const unsigned short* __restrict__ Q,
    const unsigned short* __restrict__ Kg,
    const unsigned short* __restrict__ VTg,
    unsigned short* __restrict__ O)
{
  __shared__ unsigned short Ks [2][64*128];
  __shared__ unsigned short VTs[2][128*64];

  const int tid  = threadIdx.x;
  const int lane = tid & 63, wid = tid >> 6;
  const int la   = lane & 15, hi = lane >> 4;
  const int swz  = ((int)(blockIdx.x & 7) << 6) + ((int)blockIdx.x >> 3);
  const int bh   = swz >> 4;
  const int q0   = (swz & 15) << 7;
  const int b    = bh >> 4, h = bh & 15;

  const unsigned short* Qh = Q   + (size_t)bh * SEQ * DH;
  const unsigned short* Kh = Kg  + (size_t)bh * SEQ * DH;
  const unsigned short* Vh = VTg + (size_t)bh * SEQ * DH;

  const int qrow = q0 + wid * 32;

  bf16x8 qf[2][4];
  #pragma unroll
  for (int qi = 0; qi < 2; qi++)
    #pragma unroll
    for (int ks = 0; ks < 4; ks++)
      qf[qi][ks] = *(const bf16x8*)(Qh + (size_t)(qrow + qi*16 + la)*DH + ks*32 + hi*8);

  f32x4 o[2][8];
  float mrun[2], lrun[2];
  #pragma unroll
  for (int qi = 0; qi < 2; qi++) {
    #pragma unroll
    for (int df = 0; df < 8; df++) o[qi][df] = f32x4{0.f,0.f,0.f,0.f};
    mrun[qi] = -1e30f; lrun[qi] = 0.f;
  }

  #pragma unroll
  for (int i = 0; i < 4; i++) {
    int off = i*4096 + tid*16;
    gload16((char*)Ks[0]  + off, (const char*)Kh + off);
    gload16((char*)VTs[0] + off, (const char*)Vh + off);
  }
  __syncthreads();

  /* log2-domain scale: log2(e)/sqrt(128) */
  const float sc2 = 0.1275424483f;

  #pragma unroll 1
  for (int t = 0; t < SEQ/64; ++t) {
    const int cur = t & 1;

    if (t + 1 < SEQ/64) {
      const char* kt = (const char*)(Kh + (size_t)(t+1)*(64*DH));
      const char* vt = (const char*)(Vh + (size_t)(t+1)*(64*DH));
      #pragma unroll
      for (int i = 0; i < 4; i++) {
        int off = i*4096 + tid*16;
        gload16((char*)Ks[cur^1]  + off, kt + off);
        gload16((char*)VTs[cur^1] + off, vt + off);
      }
    }

    /* S^T[kv][q] = K Q^T : S[mf][qi], kv = mf*16+hi*4+r, q = qi*16+la */
    f32x4 S[4][2];
    #pragma unroll
    for (int mf = 0; mf < 4; mf++)
      #pragma unroll
      for (int qi = 0; qi < 2; qi++) S[mf][qi] = f32x4{0.f,0.f,0.f,0.f};
    #pragma unroll
    for (int ks = 0; ks < 4; ks++) {
      bf16x8 kf[4];
      #pragma unroll
      for (int mf = 0; mf < 4; mf++) {
        int boff = (((mf*16 + la) << 8) + (ks << 6) + (hi << 4)) ^ ((la & 7) << 4);
        kf[mf] = *(const bf16x8*)((const char*)Ks[cur] + boff);
      }
      #pragma unroll
      for (int mf = 0; mf < 4; mf++)
        #pragma unroll
        for (int qi = 0; qi < 2; qi++)
          S[mf][qi] = __builtin_amdgcn_mfma_f32_16x16x32_bf16(kf[mf], qf[qi][ks], S[mf][qi], 0, 0, 0);
    }

    unsigned int pf[2][2][4];
    #pragma unroll
    for (int qi = 0; qi < 2; qi++) {
      float pm = S[0][qi][0];
      #pragma unroll
      for (int mf = 0; mf < 4; mf++)
        #pragma unroll
        for (int r = 0; r < 4; r++) pm = fmaxf(pm, S[mf][qi][r]);
      pm = fmaxf(pm, __shfl_xor(pm, 16));
      pm = fmaxf(pm, __shfl_xor(pm, 32));
      pm *= sc2;

      float mn;
      if (__all(pm <= mrun[qi] + 8.0f)) {
        mn = mrun[qi];
      } else {
        mn = fmaxf(mrun[qi], pm);
        float alpha = __builtin_amdgcn_exp2f(mrun[qi] - mn);
        mrun[qi] = mn;
        lrun[qi] *= alpha;
        #pragma unroll
        for (int r = 0; r < 4; r++) {
          float ar = __shfl(alpha, (lane & 48) | ((hi << 2) | r), 64);
          #pragma unroll
          for (int df = 0; df < 8; df++) o[qi][df][r] *= ar;
        }
      }

      float p[4][4]; float rs = 0.f;
      #pragma unroll
      for (int mf = 0; mf < 4; mf++)
        #pragma unroll
        for (int r = 0; r < 4; r++) {
          float e = __builtin_amdgcn_exp2f(fmaf(S[mf][qi][r], sc2, -mn));
          p[mf][r] = e; rs += e;
        }
      rs += __shfl_xor(rs, 16);
      rs += __shfl_xor(rs, 32);
      lrun[qi] += rs;

      unsigned int c[4][2];
      #pragma unroll
      for (int mf = 0; mf < 4; mf++) {
        c[mf][0] = cvtpk_bf16(p[mf][0], p[mf][1]);
        c[mf][1] = cvtpk_bf16(p[mf][2], p[mf][3]);
      }
      #pragma unroll
      for (int ks2 = 0; ks2 < 2; ks2++) {
        #pragma unroll
        for (int w = 0; w < 4; w++) {
          int src = la + 16*(2*(hi & 1) + (w >> 1));
          unsigned int t0 = __shfl(c[2*ks2    ][w & 1], src, 64);
          unsigned int t1 = __shfl(c[2*ks2 + 1][w & 1], src, 64);
          pf[qi][ks2][w] = (hi >> 1) ? t1 : t0;
        }
      }
    }

    #pragma unroll
    for (int ks2 = 0; ks2 < 2; ks2++) {
      #pragma unroll
      for (int df = 0; df < 8; df++) {
        int vrow = df*16 + la;
        int boff = ((vrow << 7) + (ks2 << 6) + (hi << 4)) ^ ((la & 7) << 4);
        bf16x8 vf = *(const bf16x8*)((const char*)VTs[cur] + boff);
        #pragma unroll
        for (int qi = 0; qi < 2; qi++) {
          u32x4 pw = {pf[qi][ks2][0], pf[qi][ks2][1], pf[qi][ks2][2], pf[qi][ks2][3]};
          o[qi][df] = __builtin_amdgcn_mfma_f32_16x16x32_bf16(
              __builtin_bit_cast(bf16x8, pw), vf, o[qi][df], 0, 0, 0);
        }
      }
    }
    __syncthreads();
  }

  unsigned short* Ob = O + (size_t)b * SEQ * D_MODEL + h * DH;
  #pragma unroll
  for (int qi = 0; qi < 2; qi++) {
    float linv[4];
    #pragma unroll
    for (int r = 0; r < 4; r++)
      linv[r] = 1.0f / __shfl(lrun[qi], (lane & 48) | ((hi << 2) | r), 64);
    #pragma unroll
    for (int df = 0; df < 8; df++)
      #pragma unroll
      for (int r = 0; r < 4; r++) {
        int srow = qrow + qi*16 + hi*4 + r;
        Ob[(size_t)srow * D_MODEL + df*16 + la] = f2bf(o[qi][df][r] * linv[r]);
      }
  }
}

/* ---------------- launcher ---------------- */
extern "C" void kernel_launch(void* const* d_in, const int* in_sizes, int n_in,
                              void* d_out, int out_size, void* d_ws, size_t ws_size,
                              hipStream_t stream) {
  const float* x  = (const float*)d_in[0];
  const float* wq = (const float*)d_in[1];
  const float* bq = (const float*)d_in[2];
  const float* wk = (const float*)d_in[3];
  const float* bk = (const float*)d_in[4];
  const float* wv = (const float*)d_in[5];
  const float* bv = (const float*)d_in[6];
  const float* wo = (const float*)d_in[7];
  const float* bo = (const float*)d_in[8];
  float* out = (float*)d_out;

  const size_t X = (size_t)MROWS * D_MODEL;   /* 8388608  */
  const size_t W = (size_t)D_MODEL * D_MODEL; /* 4194304  */

  unsigned short* ws  = (unsigned short*)d_ws;
  unsigned short* xb  = ws;
  unsigned short* wqb = xb  + X;   /* wqb,wkb,wvb,wob contiguous */
  unsigned short* wkb = wqb + W;
  unsigned short* wvb = wkb + W;
  unsigned short* wob = wvb + W;
  unsigned short* qb  = wob + W;
  unsigned short* kb  = qb  + X;
  unsigned short* vtg = kb  + X;
  unsigned short* ab  = vtg + X;

  cast_all<<<dim3(12288), 256, 0, stream>>>(x, wq, wk, wv, wo, xb, wqb);

  /* fused QKV: M=4096, N=6144, 256x192 tiles -> 16x32 = 512 blocks
     (2 exact CU-rounds at 1 block/CU) */
  gemm192<<<dim3(512), 512, 0, stream>>>(xb, wqb, bq, bk, bv, qb, kb, vtg);

  attn_fwd<<<dim3(512), 256, 0, stream>>>(qb, kb, vtg, ab);

  /* out-proj: M=4096, N=2048 -> 32x8 = 256 blocks (1 exact CU-round) */
  gemm256<<<dim3(256), 512, 0, stream>>>(ab, wob, bo, out, 1);
}

// Round 14
// 276.993 us; speedup vs baseline: 1.0034x; 1.0034x over previous
//
#include <hip/hip_runtime.h>

#define D_MODEL 2048
#define SEQ     2048
#define NB      2
#define NH      16
#define DH      128
#define MROWS   (NB*SEQ)   /* 4096 */
#define GK      2048       /* K dim of all GEMMs */
#define NT      (GK/64)    /* 32 K-tiles */

typedef __bf16 bf16x8 __attribute__((ext_vector_type(8)));
typedef float  f32x4  __attribute__((ext_vector_type(4)));
typedef unsigned short ushort8 __attribute__((ext_vector_type(8)));
typedef unsigned int   u32x4   __attribute__((ext_vector_type(4)));

__device__ __forceinline__ unsigned short f2bf(float f) {
  unsigned int u = __float_as_uint(f);
  u += 0x7FFFu + ((u >> 16) & 1u);
  return (unsigned short)(u >> 16);
}

__device__ __forceinline__ unsigned int cvtpk_bf16(float lo, float hi) {
  unsigned int r;
  asm("v_cvt_pk_bf16_f32 %0, %1, %2" : "=v"(r) : "v"(lo), "v"(hi));
  return r;
}

__device__ __forceinline__ void gload16(void* lds, const void* g) {
  __builtin_amdgcn_global_load_lds(
      (__attribute__((address_space(1))) void*)(g),
      (__attribute__((address_space(3))) void*)(lds), 16, 0, 0);
}

/* ---- fused cast: blocks 0-4095 = x (fp32->bf16), 4096-12287 = wq|wk|wv|wo */
__global__ __launch_bounds__(256) void cast_all(
    const float* __restrict__ x,
    const float* __restrict__ w0, const float* __restrict__ w1,
    const float* __restrict__ w2, const float* __restrict__ w3,
    unsigned short* __restrict__ xb, unsigned short* __restrict__ wb) {
  int gb = blockIdx.x;
  const float* src;
  unsigned short* dst;
  int i;
  if (gb < 4096) {
    src = x; dst = xb; i = gb * 256 + threadIdx.x;
  } else {
    int g2 = gb - 4096;
    int which = g2 >> 11;
    src = (which == 0) ? w0 : (which == 1) ? w1 : (which == 2) ? w2 : w3;
    dst = wb + (size_t)which * 4194304;
    i = (g2 & 2047) * 256 + threadIdx.x;
  }
  const float4* p = (const float4*)src;
  float4 a = p[2*i], b = p[2*i+1];
  ushort8 o;
  o[0]=f2bf(a.x); o[1]=f2bf(a.y); o[2]=f2bf(a.z); o[3]=f2bf(a.w);
  o[4]=f2bf(b.x); o[5]=f2bf(b.y); o[6]=f2bf(b.z); o[7]=f2bf(b.w);
  ((ushort8*)dst)[i] = o;
}

/* ---------------- QKV GEMM 256x192, BK=64, 8 waves (2Mx4N), wave-tile
   128x48, 2-slot LDS (112KB), stage-all-at-top + counted vmcnt(7) (r12
   ledger), zero-conflict XOR swizzle, bn-major XCD map, grid 512 = 2 exact
   CU-rounds.  r14: barrier-minimal body — 2 barriers/tile only (top
   availability + trailing reuse-fence); no mid-phase barriers, no inline
   lgkm drains: compiler emits fine-grained lgkmcnt and waves drift so one
   wave's ds_reads overlap another's MFMAs (m114).                          */
__global__ __launch_bounds__(512, 2) void gemm192(
    const unsigned short* __restrict__ A,
    const unsigned short* __restrict__ B,
    const float* __restrict__ b0, const float* __restrict__ b1,
    const float* __restrict__ b2,
    unsigned short* __restrict__ qo, unsigned short* __restrict__ ko,
    unsigned short* __restrict__ vo)
{
  __shared__ char lds[2*57344];   /* slot: A 32KB [256][64] + B 24KB [192][64] */

  const int tid  = threadIdx.x;
  const int lane = tid & 63, wid = tid >> 6;
  const int la   = lane & 15, hi = lane >> 4;
  const int wm   = wid >> 2,  wn = wid & 3;

  const int xcd = (int)blockIdx.x & 7, ii = (int)blockIdx.x >> 3;
  const int bm  = ii >> 2;            /* 16 M-tiles, A-panel-sharing adjacent */
  const int bn  = xcd * 4 + (ii & 3); /* 4 B-panels per XCD (~3MB in L2)      */

  const unsigned short* Ab = A + (size_t)(bm*256) * GK;
  const unsigned short* Bb = B + (size_t)(bn*192) * GK;

  f32x4 acc[8][3];
  #pragma unroll
  for (int m = 0; m < 8; m++)
    #pragma unroll
    for (int n = 0; n < 3; n++) acc[m][n] = f32x4{0.f,0.f,0.f,0.f};

#define STG(slot, kt) do {                                                    \
    char* base_ = lds + (slot)*57344;                                         \
    _Pragma("unroll")                                                         \
    for (int j = 0; j < 4; j++) {                                             \
      int idx = j*512 + tid;                                                  \
      int row = idx >> 3;                                                     \
      int c   = (idx & 7) << 4;                                               \
      gload16(base_ + idx*16,                                                 \
              Ab + (size_t)row*GK + (kt)*64 + ((c ^ ((row&7)<<4)) >> 1));     \
    }                                                                         \
    _Pragma("unroll")                                                         \
    for (int j = 0; j < 3; j++) {                                             \
      int idx = j*512 + tid;                                                  \
      int row = idx >> 3;                                                     \
      int c   = (idx & 7) << 4;                                               \
      gload16(base_ + 32768 + idx*16,                                         \
              Bb + (size_t)row*GK + (kt)*64 + ((c ^ ((row&7)<<4)) >> 1));     \
    }                                                                         \
  } while (0)

  STG(0, 0);
  const int xr = (la & 7) << 4;

  #pragma unroll 1
  for (int t = 0; t < NT; ++t) {
    /* stage t+1 into the slot fenced by iter t-1's trailing barrier; wait
       for tile t with t+1's 7 loads left in flight (never drain mid-loop) */
    if (t + 1 < NT) {
      STG((t+1)&1, t+1);
      asm volatile("s_waitcnt vmcnt(7)" ::: "memory");
    } else {
      asm volatile("s_waitcnt vmcnt(0)" ::: "memory");
    }
    __builtin_amdgcn_s_barrier();
    asm volatile("" ::: "memory");

    const char* sa  = lds + (t&1)*57344;
    const char* sbp = sa + 32768;

    /* frag reads + MFMAs, compiler-scheduled (fine-grained lgkmcnt) */
    bf16x8 bfr[3][2], aa[8][2];
    #pragma unroll
    for (int n = 0; n < 3; n++)
      #pragma unroll
      for (int ks = 0; ks < 2; ks++)
        bfr[n][ks] = *(const bf16x8*)(sbp + (((wn*48 + n*16 + la)*128 + ks*64 + hi*16) ^ xr));
    #pragma unroll
    for (int m = 0; m < 8; m++)
      #pragma unroll
      for (int ks = 0; ks < 2; ks++)
        aa[m][ks] = *(const bf16x8*)(sa + (((wm*128 + m*16 + la)*128 + ks*64 + hi*16) ^ xr));

    __builtin_amdgcn_s_setprio(1);
    #pragma unroll
    for (int m = 0; m < 8; m++)
      #pragma unroll
      for (int n = 0; n < 3; n++)
        #pragma unroll
        for (int ks = 0; ks < 2; ks++)
          acc[m][n] = __builtin_amdgcn_mfma_f32_16x16x32_bf16(aa[m][ks], bfr[n][ks], acc[m][n], 0, 0, 0);
    __builtin_amdgcn_s_setprio(0);

    asm volatile("" ::: "memory");
    __builtin_amdgcn_s_barrier();   /* trailing: fence slot reads before restage */
  }
#undef STG

  /* epilogue: mat per n-frag (192-tiles straddle q/k/v boundaries) */
  const int row0 = bm*256 + wm*128;
  const int col0 = bn*192 + wn*48;
  #pragma unroll
  for (int n = 0; n < 3; n++) {
    int col = col0 + n*16 + la;
    int mat = col >> 11;          /* 0=q 1=k 2=v, uniform across the wave */
    int c   = col & 2047;
    int h   = c >> 7, d = c & 127;
    const float* bp = (mat == 0) ? b0 : (mat == 1) ? b1 : b2;
    float bv = bp[c];
    #pragma unroll
    for (int m = 0; m < 8; m++)
      #pragma unroll
      for (int r = 0; r < 4; r++) {
        int row = row0 + m*16 + hi*4 + r;
        int bb  = row >> 11, s = row & (SEQ-1);
        unsigned short val = f2bf(acc[m][n][r] + bv);
        if (mat == 0) {
          qo[((size_t)(bb*NH + h)*SEQ + s)*DH + d] = val;
        } else if (mat == 1) {
          size_t base = ((size_t)(bb*NH + h)*SEQ + (size_t)(s >> 6)*64)*DH;
          int boff = (((s & 63) << 8) + (d << 1)) ^ ((s & 7) << 4);
          ko[base + (boff >> 1)] = val;
        } else {
          size_t base = ((size_t)(bb*NH + h)*SEQ + (size_t)(s >> 6)*64)*DH;
          int boff = ((d << 7) + ((s & 63) << 1)) ^ ((d & 7) << 4);
          vo[base + (boff >> 1)] = val;
        }
      }
  }
}

/* ---------------- out-proj GEMM 128x256 (round-6 proven, mode-1 use) ---- */
__global__ __launch_bounds__(512, 2) void gemm256(
    const unsigned short* __restrict__ A,
    const unsigned short* __restrict__ B,
    const float* __restrict__ b0,
    float* __restrict__ fo,
    int nbnx)
{
  __shared__ char lds[3*49152];

  const int tid  = threadIdx.x;
  const int lane = tid & 63, wid = tid >> 6;
  const int la   = lane & 15, hi = lane >> 4;
  const int wm   = wid >> 2,  wn = wid & 3;

  const int xcd = (int)blockIdx.x & 7, ii = (int)blockIdx.x >> 3;
  const int bm  = ii / nbnx;
  const int bn  = xcd * nbnx + ii % nbnx;

  const unsigned short* Ab = A + (size_t)(bm*128) * GK;
  const unsigned short* Bb = B + (size_t)(bn*256) * GK;

  f32x4 acc[4][4];
  #pragma unroll
  for (int m = 0; m < 4; m++)
    #pragma unroll
    for (int n = 0; n < 4; n++) acc[m][n] = f32x4{0.f,0.f,0.f,0.f};

#define STAGE_A(slot, kt) do {                                                \
    int sb_ = (slot) * 49152;                                                 \
    _Pragma("unroll")                                                         \
    for (int j = 0; j < 2; j++) {                                             \
      int idx = j*512 + tid;                                                  \
      int row = idx >> 3;                                                     \
      int c   = (idx & 7) << 4;                                               \
      gload16(lds + sb_ + idx*16,                                             \
              Ab + (size_t)row*GK + (kt)*64 + ((c ^ ((row&7)<<4)) >> 1));     \
    }                                                                         \
  } while (0)

#define STAGE_B(slot, kt) do {                                                \
    int sb_ = (slot) * 49152;                                                 \
    _Pragma("unroll")                                                         \
    for (int j = 0; j < 4; j++) {                                             \
      int idx = j*512 + tid;                                                  \
      int row = idx >> 3;                                                     \
      int c   = (idx & 7) << 4;                                               \
      gload16(lds + sb_ + 16384 + idx*16,                                     \
              Bb + (size_t)row*GK + (kt)*64 + ((c ^ ((row&7)<<4)) >> 1));     \
    }                                                                         \
  } while (0)

  STAGE_A(0, 0); STAGE_B(0, 0);
  STAGE_A(1, 1); STAGE_B(1, 1);

  int cs = 0, ps = 2;
  const int xr = (la & 7) << 4;

  #pragma unroll 1
  for (int t = 0; t < NT; ++t) {
    if (t + 1 < NT) asm volatile("s_waitcnt vmcnt(6)" ::: "memory");
    else            asm volatile("s_waitcnt vmcnt(0)" ::: "memory");
    __builtin_amdgcn_s_barrier();

    const char* sa  = lds + cs*49152;
    const char* sbp = sa + 16384;

    bf16x8 bfr[4][2], aA[2][2];
    #pragma unroll
    for (int n = 0; n < 4; n++)
      #pragma unroll
      for (int ks = 0; ks < 2; ks++)
        bfr[n][ks] = *(const bf16x8*)(sbp + (((wn*64 + n*16 + la)*128 + ks*64 + hi*16) ^ xr));
    #pragma unroll
    for (int m = 0; m < 2; m++)
      #pragma unroll
      for (int ks = 0; ks < 2; ks++)
        aA[m][ks] = *(const bf16x8*)(sa + (((wm*64 + m*16 + la)*128 + ks*64 + hi*16) ^ xr));

    if (t + 2 < NT) STAGE_A(ps, t + 2);

    asm volatile("s_waitcnt lgkmcnt(0)" ::: "memory");
    __builtin_amdgcn_sched_barrier(0);
    __builtin_amdgcn_s_setprio(1);
    #pragma unroll
    for (int m = 0; m < 2; m++)
      #pragma unroll
      for (int n = 0; n < 4; n++)
        #pragma unroll
        for (int ks = 0; ks < 2; ks++)
          acc[m][n] = __builtin_amdgcn_mfma_f32_16x16x32_bf16(aA[m][ks], bfr[n][ks], acc[m][n], 0, 0, 0);
    __builtin_amdgcn_s_setprio(0);
    __builtin_amdgcn_s_barrier();

    bf16x8 aB[2][2];
    #pragma unroll
    for (int m = 0; m < 2; m++)
      #pragma unroll
      for (int ks = 0; ks < 2; ks++)
        aB[m][ks] = *(const bf16x8*)(sa + (((wm*64 + (m+2)*16 + la)*128 + ks*64 + hi*16) ^ xr));

    if (t + 2 < NT) STAGE_B(ps, t + 2);

    asm volatile("s_waitcnt lgkmcnt(0)" ::: "memory");
    __builtin_amdgcn_sched_barrier(0);
    __builtin_amdgcn_s_setprio(1);
    #pragma unroll
    for (int m = 0; m < 2; m++)
      #pragma unroll
      for (int n = 0; n < 4; n++)
        #pragma unroll
        for (int ks = 0; ks < 2; ks++)
          acc[m+2][n] = __builtin_amdgcn_mfma_f32_16x16x32_bf16(aB[m][ks], bfr[n][ks], acc[m+2][n], 0, 0, 0);
    __builtin_amdgcn_s_setprio(0);

    cs = cs + 1; if (cs == 3) cs = 0;
    ps = ps + 1; if (ps == 3) ps = 0;
  }
#undef STAGE_A
#undef STAGE_B

  const int row0 = bm*128 + wm*64;
  const int col0 = bn*256 + wn*64;
  #pragma unroll
  for (int n = 0; n < 4; n++) {
    int col = col0 + n*16 + la;
    float bv = b0[col];
    #pragma unroll
    for (int m = 0; m < 4; m++)
      #pragma unroll
      for (int r = 0; r < 4; r++) {
        int row = row0 + m*16 + hi*4 + r;
        fo[(size_t)row*D_MODEL + col] = acc[m][n][r] + bv;
      }
  }
}

/* ---------------- flash attention fwd (round-10 proven: T13 defer-max +
   exp2-domain softmax) ---------------- */
__global__ __launch_bounds__(256, 2) void attn_fwd(
    const unsigned short* __restrict__ Q,
    const unsigned short* __restrict__ Kg,
    const unsigned short* __restrict__ VTg,
    unsigned short* __restrict__ O)
{
  __shared__ unsigned short Ks [2][64*128];
  __shared__ unsigned short VTs[2][128*64];

  const int tid  = threadIdx.x;
  const int lane = tid & 63, wid = tid >> 6;
  const int la   = lane & 15, hi = lane >> 4;
  const int swz  = ((int)(blockIdx.x & 7) << 6) + ((int)blockIdx.x >> 3);
  const int bh   = swz >> 4;
  const int q0   = (swz & 15) << 7;
  const int b    = bh >> 4, h = bh & 15;

  const unsigned short* Qh = Q   + (size_t)bh * SEQ * DH;
  const unsigned short* Kh = Kg  + (size_t)bh * SEQ * DH;
  const unsigned short* Vh = VTg + (size_t)bh * SEQ * DH;

  const int qrow = q0 + wid * 32;

  bf16x8 qf[2][4];
  #pragma unroll
  for (int qi = 0; qi < 2; qi++)
    #pragma unroll
    for (int ks = 0; ks < 4; ks++)
      qf[qi][ks] = *(const bf16x8*)(Qh + (size_t)(qrow + qi*16 + la)*DH + ks*32 + hi*8);

  f32x4 o[2][8];
  float mrun[2], lrun[2];
  #pragma unroll
  for (int qi = 0; qi < 2; qi++) {
    #pragma unroll
    for (int df = 0; df < 8; df++) o[qi][df] = f32x4{0.f,0.f,0.f,0.f};
    mrun[qi] = -1e30f; lrun[qi] = 0.f;
  }

  #pragma unroll
  for (int i = 0; i < 4; i++) {
    int off = i*4096 + tid*16;
    gload16((char*)Ks[0]  + off, (const char*)Kh + off);
    gload16((char*)VTs[0] + off, (const char*)Vh + off);
  }
  __syncthreads();

  /* log2-domain scale: log2(e)/sqrt(128) */
  const float sc2 = 0.1275424483f;

  #pragma unroll 1
  for (int t = 0; t < SEQ/64; ++t) {
    const int cur = t & 1;

    if (t + 1 < SEQ/64) {
      const char* kt = (const char*)(Kh + (size_t)(t+1)*(64*DH));
      const char* vt = (const char*)(Vh + (size_t)(t+1)*(64*DH));
      #pragma unroll
      for (int i = 0; i < 4; i++) {
        int off = i*4096 + tid*16;
        gload16((char*)Ks[cur^1]  + off, kt + off);
        gload16((char*)VTs[cur^1] + off, vt + off);
      }
    }

    /* S^T[kv][q] = K Q^T : S[mf][qi], kv = mf*16+hi*4+r, q = qi*16+la */
    f32x4 S[4][2];
    #pragma unroll
    for (int mf = 0; mf < 4; mf++)
      #pragma unroll
      for (int qi = 0; qi < 2; qi++) S[mf][qi] = f32x4{0.f,0.f,0.f,0.f};
    #pragma unroll
    for (int ks = 0; ks < 4; ks++) {
      bf16x8 kf[4];
      #pragma unroll
      for (int mf = 0; mf < 4; mf++) {
        int boff = (((mf*16 + la) << 8) + (ks << 6) + (hi << 4)) ^ ((la & 7) << 4);
        kf[mf] = *(const bf16x8*)((const char*)Ks[cur] + boff);
      }
      #pragma unroll
      for (int mf = 0; mf < 4; mf++)
        #pragma unroll
        for (int qi = 0; qi < 2; qi++)
          S[mf][qi] = __builtin_amdgcn_mfma_f32_16x16x32_bf16(kf[mf], qf[qi][ks], S[mf][qi], 0, 0, 0);
    }

    unsigned int pf[2][2][4];
    #pragma unroll
    for (int qi = 0; qi < 2; qi++) {
      float pm = S[0][qi][0];
      #pragma unroll
      for (int mf = 0; mf < 4; mf++)
        #pragma unroll
        for (int r = 0; r < 4; r++) pm = fmaxf(pm, S[mf][qi][r]);
      pm = fmaxf(pm, __shfl_xor(pm, 16));
      pm = fmaxf(pm, __shfl_xor(pm, 32));
      pm *= sc2;

      float mn;
      if (__all(pm <= mrun[qi] + 8.0f)) {
        mn = mrun[qi];
      } else {
        mn = fmaxf(mrun[qi], pm);
        float alpha = __builtin_amdgcn_exp2f(mrun[qi] - mn);
        mrun[qi] = mn;
        lrun[qi] *= alpha;
        #pragma unroll
        for (int r = 0; r < 4; r++) {
          float ar = __shfl(alpha, (lane & 48) | ((hi << 2) | r), 64);
          #pragma unroll
          for (int df = 0; df < 8; df++) o[qi][df][r] *= ar;
        }
      }

      float p[4][4]; float rs = 0.f;
      #pragma unroll
      for (int mf = 0; mf < 4; mf++)
        #pragma unroll
        for (int r = 0; r < 4; r++) {
          float e = __builtin_amdgcn_exp2f(fmaf(S[mf][qi][r], sc2, -mn));
          p[mf][r] = e; rs += e;
        }
      rs += __shfl_xor(rs, 16);
      rs += __shfl_xor(rs, 32);
      lrun[qi] += rs;

      unsigned int c[4][2];
      #pragma unroll
      for (int mf = 0; mf < 4; mf++) {
        c[mf][0] = cvtpk_bf16(p[mf][0], p[mf][1]);
        c[mf][1] = cvtpk_bf16(p[mf][2], p[mf][3]);
      }
      #pragma unroll
      for (int ks2 = 0; ks2 < 2; ks2++) {
        #pragma unroll
        for (int w = 0; w < 4; w++) {
          int src = la + 16*(2*(hi & 1) + (w >> 1));
          unsigned int t0 = __shfl(c[2*ks2    ][w & 1], src, 64);
          unsigned int t1 = __shfl(c[2*ks2 + 1][w & 1], src, 64);
          pf[qi][ks2][w] = (hi >> 1) ? t1 : t0;
        }
      }
    }

    #pragma unroll
    for (int ks2 = 0; ks2 < 2; ks2++) {
      #pragma unroll
      for (int df = 0; df < 8; df++) {
        int vrow = df*16 + la;
        int boff = ((vrow << 7) + (ks2 << 6) + (hi << 4)) ^ ((la & 7) << 4);
        bf16x8 vf = *(const bf16x8*)((const char*)VTs[cur] + boff);
        #pragma unroll
        for (int qi = 0; qi < 2; qi++) {
          u32x4 pw = {pf[qi][ks2][0], pf[qi][ks2][1], pf[qi][ks2][2], pf[qi][ks2][3]};
          o[qi][df] = __builtin_amdgcn_mfma_f32_16x16x32_bf16(
              __builtin_bit_cast(bf16x8, pw), vf, o[qi][df], 0, 0, 0);
        }
      }
    }
    __syncthreads();
  }

  unsigned short* Ob = O + (size_t)b * SEQ * D_MODEL + h * DH;
  #pragma unroll
  for (int qi = 0; qi < 2; qi++) {
    float linv[4];
    #pragma unroll
    for (int r = 0; r < 4; r++)
      linv[r] = 1.0f / __shfl(lrun[qi], (lane & 48) | ((hi << 2) | r), 64);
    #pragma unroll
    for (int df = 0; df < 8; df++)
      #pragma unroll
      for (int r = 0; r < 4; r++) {
        int srow = qrow + qi*16 + hi*4 + r;
        Ob[(size_t)srow * D_MODEL + df*16 + la] = f2bf(o[qi][df][r] * linv[r]);
      }
  }
}

/* ---------------- launcher ---------------- */
extern "C" void kernel_launch(void* const* d_in, const int* in_sizes, int n_in,
                              void* d_out, int out_size, void* d_ws, size_t ws_size,
                              hipStream_t stream) {
  const float* x  = (const float*)d_in[0];
  const float* wq = (const float*)d_in[1];
  const float* bq = (const float*)d_in[2];
  const float* wk = (const float*)d_in[3];
  const float* bk = (const float*)d_in[4];
  const float* wv = (const float*)d_in[5];
  const float* bv = (const float*)d_in[6];
  const float* wo = (const float*)d_in[7];
  const float* bo = (const float*)d_in[8];
  float* out = (float*)d_out;

  const size_t X = (size_t)MROWS * D_MODEL;   /* 8388608  */
  const size_t W = (size_t)D_MODEL * D_MODEL; /* 4194304  */

  unsigned short* ws  = (unsigned short*)d_ws;
  unsigned short* xb  = ws;
  unsigned short* wqb = xb  + X;   /* wqb,wkb,wvb,wob contiguous */
  unsigned short* wkb = wqb + W;
  unsigned short* wvb = wkb + W;
  unsigned short* wob = wvb + W;
  unsigned short* qb  = wob + W;
  unsigned short* kb  = qb  + X;
  unsigned short* vtg = kb  + X;
  unsigned short* ab  = vtg + X;

  cast_all<<<dim3(12288), 256, 0, stream>>>(x, wq, wk, wv, wo, xb, wqb);

  /* fused QKV: M=4096, N=6144, 256x192 tiles -> 16x32 = 512 blocks
     (2 exact CU-rounds at 1 block/CU) */
  gemm192<<<dim3(512), 512, 0, stream>>>(xb, wqb, bq, bk, bv, qb, kb, vtg);

  attn_fwd<<<dim3(512), 256, 0, stream>>>(qb, kb, vtg, ab);

  /* out-proj: M=4096, N=2048 -> 32x8 = 256 blocks (1 exact CU-round) */
  gemm256<<<dim3(256), 512, 0, stream>>>(ab, wob, bo, out, 1);
}

// Round 15
// 273.416 us; speedup vs baseline: 1.0165x; 1.0131x over previous
//
#include <hip/hip_runtime.h>

#define D_MODEL 2048
#define SEQ     2048
#define NB      2
#define NH      16
#define DH      128
#define MROWS   (NB*SEQ)   /* 4096 */
#define GK      2048       /* K dim of all GEMMs */
#define NT      (GK/64)    /* 32 K-tiles */

typedef __bf16 bf16x8 __attribute__((ext_vector_type(8)));
typedef float  f32x4  __attribute__((ext_vector_type(4)));
typedef unsigned short ushort8 __attribute__((ext_vector_type(8)));
typedef unsigned int   u32x4   __attribute__((ext_vector_type(4)));

__device__ __forceinline__ unsigned short f2bf(float f) {
  unsigned int u = __float_as_uint(f);
  u += 0x7FFFu + ((u >> 16) & 1u);
  return (unsigned short)(u >> 16);
}

__device__ __forceinline__ unsigned int cvtpk_bf16(float lo, float hi) {
  unsigned int r;
  asm("v_cvt_pk_bf16_f32 %0, %1, %2" : "=v"(r) : "v"(lo), "v"(hi));
  return r;
}

__device__ __forceinline__ void gload16(void* lds, const void* g) {
  __builtin_amdgcn_global_load_lds(
      (__attribute__((address_space(1))) void*)(g),
      (__attribute__((address_space(3))) void*)(lds), 16, 0, 0);
}

/* ---- fused cast: blocks 0-4095 = x (fp32->bf16), 4096-12287 = wq|wk|wv|wo */
__global__ __launch_bounds__(256) void cast_all(
    const float* __restrict__ x,
    const float* __restrict__ w0, const float* __restrict__ w1,
    const float* __restrict__ w2, const float* __restrict__ w3,
    unsigned short* __restrict__ xb, unsigned short* __restrict__ wb) {
  int gb = blockIdx.x;
  const float* src;
  unsigned short* dst;
  int i;
  if (gb < 4096) {
    src = x; dst = xb; i = gb * 256 + threadIdx.x;
  } else {
    int g2 = gb - 4096;
    int which = g2 >> 11;
    src = (which == 0) ? w0 : (which == 1) ? w1 : (which == 2) ? w2 : w3;
    dst = wb + (size_t)which * 4194304;
    i = (g2 & 2047) * 256 + threadIdx.x;
  }
  const float4* p = (const float4*)src;
  float4 a = p[2*i], b = p[2*i+1];
  ushort8 o;
  o[0]=f2bf(a.x); o[1]=f2bf(a.y); o[2]=f2bf(a.z); o[3]=f2bf(a.w);
  o[4]=f2bf(b.x); o[5]=f2bf(b.y); o[6]=f2bf(b.z); o[7]=f2bf(b.w);
  ((ushort8*)dst)[i] = o;
}

/* ---------------- QKV GEMM 256x192, BK=64, 8 waves (2Mx4N), wave-tile
   128x48, 2-slot LDS (112KB), zero-conflict XOR swizzle, bn-major XCD map,
   grid 512 = 2 exact CU-rounds.
   r15: m201 phase form — 4 phases/tile, each {ds_read 4-7 frags; stage one
   quarter-unit of tile t+1; BAR; lgkm(0)+sched_barrier; setprio+12 MFMA;
   BAR}. Barrier BEFORE lgkm covers read latency; per-phase staging; only
   28 frag VGPRs live per phase so reads stay in flight.                    */
__global__ __launch_bounds__(512, 2) void gemm192(
    const unsigned short* __restrict__ A,
    const unsigned short* __restrict__ B,
    const float* __restrict__ b0, const float* __restrict__ b1,
    const float* __restrict__ b2,
    unsigned short* __restrict__ qo, unsigned short* __restrict__ ko,
    unsigned short* __restrict__ vo)
{
  __shared__ char lds[2*57344];   /* slot: A 32KB [256][64] + B 24KB [192][64] */

  const int tid  = threadIdx.x;
  const int lane = tid & 63, wid = tid >> 6;
  const int la   = lane & 15, hi = lane >> 4;
  const int wm   = wid >> 2,  wn = wid & 3;

  const int xcd = (int)blockIdx.x & 7, ii = (int)blockIdx.x >> 3;
  const int bm  = ii >> 2;            /* 16 M-tiles, A-panel-sharing adjacent */
  const int bn  = xcd * 4 + (ii & 3); /* 4 B-panels per XCD (~3MB in L2)      */

  const unsigned short* Ab = A + (size_t)(bm*256) * GK;
  const unsigned short* Bb = B + (size_t)(bn*192) * GK;

  f32x4 acc[8][3];
  #pragma unroll
  for (int m = 0; m < 8; m++)
    #pragma unroll
    for (int n = 0; n < 3; n++) acc[m][n] = f32x4{0.f,0.f,0.f,0.f};

/* staging units: exact partition of the r12-proven STG index algebra */
#define STG_AJ(base_, kt, J0, J1) do {                                        \
    _Pragma("unroll")                                                         \
    for (int j = (J0); j < (J1); j++) {                                       \
      int idx = j*512 + tid;                                                  \
      int row = idx >> 3;                                                     \
      int c   = (idx & 7) << 4;                                               \
      gload16((base_) + idx*16,                                               \
              Ab + (size_t)row*GK + (kt)*64 + ((c ^ ((row&7)<<4)) >> 1));     \
    }                                                                         \
  } while (0)

#define STG_BJ(base_, kt, J0, J1) do {                                        \
    _Pragma("unroll")                                                         \
    for (int j = (J0); j < (J1); j++) {                                       \
      int idx = j*512 + tid;                                                  \
      int row = idx >> 3;                                                     \
      int c   = (idx & 7) << 4;                                               \
      gload16((base_) + 32768 + idx*16,                                       \
              Bb + (size_t)row*GK + (kt)*64 + ((c ^ ((row&7)<<4)) >> 1));     \
    }                                                                         \
  } while (0)

  /* prologue: stage tile 0 fully */
  STG_AJ(lds, 0, 0, 4);
  STG_BJ(lds, 0, 0, 3);
  const int xr = (la & 7) << 4;

  #pragma unroll 1
  for (int t = 0; t < NT; ++t) {
    /* tile t resident: its units were issued >=1 phase ago (old) */
    asm volatile("s_waitcnt vmcnt(0)" ::: "memory");
    __builtin_amdgcn_s_barrier();

    const char* sa  = lds + (t&1)*57344;
    const char* sbp = sa + 32768;
    char* nb = lds + ((t+1)&1)*57344;
    const bool pf = (t + 1 < NT);

    bf16x8 bfr[3], aq[4];

    /* ---- phase 1: (ks0, mh0) reads + stage A0(t+1) ---- */
    #pragma unroll
    for (int n = 0; n < 3; n++)
      bfr[n] = *(const bf16x8*)(sbp + (((wn*48 + n*16 + la)*128 + hi*16) ^ xr));
    #pragma unroll
    for (int m = 0; m < 4; m++)
      aq[m] = *(const bf16x8*)(sa + (((wm*128 + m*16 + la)*128 + hi*16) ^ xr));
    if (pf) STG_AJ(nb, t+1, 0, 2);
    __builtin_amdgcn_s_barrier();
    asm volatile("s_waitcnt lgkmcnt(0)" ::: "memory");
    __builtin_amdgcn_sched_barrier(0);
    __builtin_amdgcn_s_setprio(1);
    #pragma unroll
    for (int m = 0; m < 4; m++)
      #pragma unroll
      for (int n = 0; n < 3; n++)
        acc[m][n] = __builtin_amdgcn_mfma_f32_16x16x32_bf16(aq[m], bfr[n], acc[m][n], 0, 0, 0);
    __builtin_amdgcn_s_setprio(0);
    __builtin_amdgcn_s_barrier();

    /* ---- phase 2: (ks0, mh1) reads (B persists) + stage A1(t+1) ---- */
    #pragma unroll
    for (int m = 0; m < 4; m++)
      aq[m] = *(const bf16x8*)(sa + (((wm*128 + (m+4)*16 + la)*128 + hi*16) ^ xr));
    if (pf) STG_AJ(nb, t+1, 2, 4);
    __builtin_amdgcn_s_barrier();
    asm volatile("s_waitcnt lgkmcnt(0)" ::: "memory");
    __builtin_amdgcn_sched_barrier(0);
    __builtin_amdgcn_s_setprio(1);
    #pragma unroll
    for (int m = 0; m < 4; m++)
      #pragma unroll
      for (int n = 0; n < 3; n++)
        acc[m+4][n] = __builtin_amdgcn_mfma_f32_16x16x32_bf16(aq[m], bfr[n], acc[m+4][n], 0, 0, 0);
    __builtin_amdgcn_s_setprio(0);
    __builtin_amdgcn_s_barrier();

    /* ---- phase 3: (ks1, mh0) reads + stage B01(t+1) ---- */
    #pragma unroll
    for (int n = 0; n < 3; n++)
      bfr[n] = *(const bf16x8*)(sbp + (((wn*48 + n*16 + la)*128 + 64 + hi*16) ^ xr));
    #pragma unroll
    for (int m = 0; m < 4; m++)
      aq[m] = *(const bf16x8*)(sa + (((wm*128 + m*16 + la)*128 + 64 + hi*16) ^ xr));
    if (pf) STG_BJ(nb, t+1, 0, 2);
    __builtin_amdgcn_s_barrier();
    asm volatile("s_waitcnt lgkmcnt(0)" ::: "memory");
    __builtin_amdgcn_sched_barrier(0);
    __builtin_amdgcn_s_setprio(1);
    #pragma unroll
    for (int m = 0; m < 4; m++)
      #pragma unroll
      for (int n = 0; n < 3; n++)
        acc[m][n] = __builtin_amdgcn_mfma_f32_16x16x32_bf16(aq[m], bfr[n], acc[m][n], 0, 0, 0);
    __builtin_amdgcn_s_setprio(0);
    __builtin_amdgcn_s_barrier();

    /* ---- phase 4: (ks1, mh1) reads + stage B2(t+1) ---- */
    #pragma unroll
    for (int m = 0; m < 4; m++)
      aq[m] = *(const bf16x8*)(sa + (((wm*128 + (m+4)*16 + la)*128 + 64 + hi*16) ^ xr));
    if (pf) STG_BJ(nb, t+1, 2, 3);
    __builtin_amdgcn_s_barrier();
    asm volatile("s_waitcnt lgkmcnt(0)" ::: "memory");
    __builtin_amdgcn_sched_barrier(0);
    __builtin_amdgcn_s_setprio(1);
    #pragma unroll
    for (int m = 0; m < 4; m++)
      #pragma unroll
      for (int n = 0; n < 3; n++)
        acc[m+4][n] = __builtin_amdgcn_mfma_f32_16x16x32_bf16(aq[m], bfr[n], acc[m+4][n], 0, 0, 0);
    __builtin_amdgcn_s_setprio(0);
    __builtin_amdgcn_s_barrier();   /* fence slot-t reads before its restage */
  }
#undef STG_AJ
#undef STG_BJ

  /* epilogue: mat per n-frag (192-tiles straddle q/k/v boundaries) */
  const int row0 = bm*256 + wm*128;
  const int col0 = bn*192 + wn*48;
  #pragma unroll
  for (int n = 0; n < 3; n++) {
    int col = col0 + n*16 + la;
    int mat = col >> 11;          /* 0=q 1=k 2=v, uniform across the wave */
    int c   = col & 2047;
    int h   = c >> 7, d = c & 127;
    const float* bp = (mat == 0) ? b0 : (mat == 1) ? b1 : b2;
    float bv = bp[c];
    #pragma unroll
    for (int m = 0; m < 8; m++)
      #pragma unroll
      for (int r = 0; r < 4; r++) {
        int row = row0 + m*16 + hi*4 + r;
        int bb  = row >> 11, s = row & (SEQ-1);
        unsigned short val = f2bf(acc[m][n][r] + bv);
        if (mat == 0) {
          qo[((size_t)(bb*NH + h)*SEQ + s)*DH + d] = val;
        } else if (mat == 1) {
          size_t base = ((size_t)(bb*NH + h)*SEQ + (size_t)(s >> 6)*64)*DH;
          int boff = (((s & 63) << 8) + (d << 1)) ^ ((s & 7) << 4);
          ko[base + (boff >> 1)] = val;
        } else {
          size_t base = ((size_t)(bb*NH + h)*SEQ + (size_t)(s >> 6)*64)*DH;
          int boff = ((d << 7) + ((s & 63) << 1)) ^ ((d & 7) << 4);
          vo[base + (boff >> 1)] = val;
        }
      }
  }
}

/* ---------------- out-proj GEMM 128x256 (round-6 proven, mode-1 use) ---- */
__global__ __launch_bounds__(512, 2) void gemm256(
    const unsigned short* __restrict__ A,
    const unsigned short* __restrict__ B,
    const float* __restrict__ b0,
    float* __restrict__ fo,
    int nbnx)
{
  __shared__ char lds[3*49152];

  const int tid  = threadIdx.x;
  const int lane = tid & 63, wid = tid >> 6;
  const int la   = lane & 15, hi = lane >> 4;
  const int wm   = wid >> 2,  wn = wid & 3;

  const int xcd = (int)blockIdx.x & 7, ii = (int)blockIdx.x >> 3;
  const int bm  = ii / nbnx;
  const int bn  = xcd * nbnx + ii % nbnx;

  const unsigned short* Ab = A + (size_t)(bm*128) * GK;
  const unsigned short* Bb = B + (size_t)(bn*256) * GK;

  f32x4 acc[4][4];
  #pragma unroll
  for (int m = 0; m < 4; m++)
    #pragma unroll
    for (int n = 0; n < 4; n++) acc[m][n] = f32x4{0.f,0.f,0.f,0.f};

#define STAGE_A(slot, kt) do {                                                \
    int sb_ = (slot) * 49152;                                                 \
    _Pragma("unroll")                                                         \
    for (int j = 0; j < 2; j++) {                                             \
      int idx = j*512 + tid;                                                  \
      int row = idx >> 3;                                                     \
      int c   = (idx & 7) << 4;                                               \
      gload16(lds + sb_ + idx*16,                                             \
              Ab + (size_t)row*GK + (kt)*64 + ((c ^ ((row&7)<<4)) >> 1));     \
    }                                                                         \
  } while (0)

#define STAGE_B(slot, kt) do {                                                \
    int sb_ = (slot) * 49152;                                                 \
    _Pragma("unroll")                                                         \
    for (int j = 0; j < 4; j++) {                                             \
      int idx = j*512 + tid;                                                  \
      int row = idx >> 3;                                                     \
      int c   = (idx & 7) << 4;                                               \
      gload16(lds + sb_ + 16384 + idx*16,                                     \
              Bb + (size_t)row*GK + (kt)*64 + ((c ^ ((row&7)<<4)) >> 1));     \
    }                                                                         \
  } while (0)

  STAGE_A(0, 0); STAGE_B(0, 0);
  STAGE_A(1, 1); STAGE_B(1, 1);

  int cs = 0, ps = 2;
  const int xr = (la & 7) << 4;

  #pragma unroll 1
  for (int t = 0; t < NT; ++t) {
    if (t + 1 < NT) asm volatile("s_waitcnt vmcnt(6)" ::: "memory");
    else            asm volatile("s_waitcnt vmcnt(0)" ::: "memory");
    __builtin_amdgcn_s_barrier();

    const char* sa  = lds + cs*49152;
    const char* sbp = sa + 16384;

    bf16x8 bfr[4][2], aA[2][2];
    #pragma unroll
    for (int n = 0; n < 4; n++)
      #pragma unroll
      for (int ks = 0; ks < 2; ks++)
        bfr[n][ks] = *(const bf16x8*)(sbp + (((wn*64 + n*16 + la)*128 + ks*64 + hi*16) ^ xr));
    #pragma unroll
    for (int m = 0; m < 2; m++)
      #pragma unroll
      for (int ks = 0; ks < 2; ks++)
        aA[m][ks] = *(const bf16x8*)(sa + (((wm*64 + m*16 + la)*128 + ks*64 + hi*16) ^ xr));

    if (t + 2 < NT) STAGE_A(ps, t + 2);

    asm volatile("s_waitcnt lgkmcnt(0)" ::: "memory");
    __builtin_amdgcn_sched_barrier(0);
    __builtin_amdgcn_s_setprio(1);
    #pragma unroll
    for (int m = 0; m < 2; m++)
      #pragma unroll
      for (int n = 0; n < 4; n++)
        #pragma unroll
        for (int ks = 0; ks < 2; ks++)
          acc[m][n] = __builtin_amdgcn_mfma_f32_16x16x32_bf16(aA[m][ks], bfr[n][ks], acc[m][n], 0, 0, 0);
    __builtin_amdgcn_s_setprio(0);
    __builtin_amdgcn_s_barrier();

    bf16x8 aB[2][2];
    #pragma unroll
    for (int m = 0; m < 2; m++)
      #pragma unroll
      for (int ks = 0; ks < 2; ks++)
        aB[m][ks] = *(const bf16x8*)(sa + (((wm*64 + (m+2)*16 + la)*128 + ks*64 + hi*16) ^ xr));

    if (t + 2 < NT) STAGE_B(ps, t + 2);

    asm volatile("s_waitcnt lgkmcnt(0)" ::: "memory");
    __builtin_amdgcn_sched_barrier(0);
    __builtin_amdgcn_s_setprio(1);
    #pragma unroll
    for (int m = 0; m < 2; m++)
      #pragma unroll
      for (int n = 0; n < 4; n++)
        #pragma unroll
        for (int ks = 0; ks < 2; ks++)
          acc[m+2][n] = __builtin_amdgcn_mfma_f32_16x16x32_bf16(aB[m][ks], bfr[n][ks], acc[m+2][n], 0, 0, 0);
    __builtin_amdgcn_s_setprio(0);

    cs = cs + 1; if (cs == 3) cs = 0;
    ps = ps + 1; if (ps == 3) ps = 0;
  }
#undef STAGE_A
#undef STAGE_B

  const int row0 = bm*128 + wm*64;
  const int col0 = bn*256 + wn*64;
  #pragma unroll
  for (int n = 0; n < 4; n++) {
    int col = col0 + n*16 + la;
    float bv = b0[col];
    #pragma unroll
    for (int m = 0; m < 4; m++)
      #pragma unroll
      for (int r = 0; r < 4; r++) {
        int row = row0 + m*16 + hi*4 + r;
        fo[(size_t)row*D_MODEL + col] = acc[m][n][r] + bv;
      }
  }
}

/* ---------------- flash attention fwd (round-10 proven: T13 defer-max +
   exp2-domain softmax) ---------------- */
__global__ __launch_bounds__(256, 2) void attn_fwd(
    const unsigned short* __restrict__ Q,
    const unsigned short* __restrict__ Kg,
    const unsigned short* __restrict__ VTg,
    unsigned short* __restrict__ O)
{
  __shared__ unsigned short Ks [2][64*128];
  __shared__ unsigned short VTs[2][128*64];

  const int tid  = threadIdx.x;
  const int lane = tid & 63, wid = tid >> 6;
  const int la   = lane & 15, hi = lane >> 4;
  const int swz  = ((int)(blockIdx.x & 7) << 6) + ((int)blockIdx.x >> 3);
  const int bh   = swz >> 4;
  const int q0   = (swz & 15) << 7;
  const int b    = bh >> 4, h = bh & 15;

  const unsigned short* Qh = Q   + (size_t)bh * SEQ * DH;
  const unsigned short* Kh = Kg  + (size_t)bh * SEQ * DH;
  const unsigned short* Vh = VTg + (size_t)bh * SEQ * DH;

  const int qrow = q0 + wid * 32;

  bf16x8 qf[2][4];
  #pragma unroll
  for (int qi = 0; qi < 2; qi++)
    #pragma unroll
    for (int ks = 0; ks < 4; ks++)
      qf[qi][ks] = *(const bf16x8*)(Qh + (size_t)(qrow + qi*16 + la)*DH + ks*32 + hi*8);

  f32x4 o[2][8];
  float mrun[2], lrun[2];
  #pragma unroll
  for (int qi = 0; qi < 2; qi++) {
    #pragma unroll
    for (int df = 0; df < 8; df++) o[qi][df] = f32x4{0.f,0.f,0.f,0.f};
    mrun[qi] = -1e30f; lrun[qi] = 0.f;
  }

  #pragma unroll
  for (int i = 0; i < 4; i++) {
    int off = i*4096 + tid*16;
    gload16((char*)Ks[0]  + off, (const char*)Kh + off);
    gload16((char*)VTs[0] + off, (const char*)Vh + off);
  }
  __syncthreads();

  /* log2-domain scale: log2(e)/sqrt(128) */
  const float sc2 = 0.1275424483f;

  #pragma unroll 1
  for (int t = 0; t < SEQ/64; ++t) {
    const int cur = t & 1;

    if (t + 1 < SEQ/64) {
      const char* kt = (const char*)(Kh + (size_t)(t+1)*(64*DH));
      const char* vt = (const char*)(Vh + (size_t)(t+1)*(64*DH));
      #pragma unroll
      for (int i = 0; i < 4; i++) {
        int off = i*4096 + tid*16;
        gload16((char*)Ks[cur^1]  + off, kt + off);
        gload16((char*)VTs[cur^1] + off, vt + off);
      }
    }

    /* S^T[kv][q] = K Q^T : S[mf][qi], kv = mf*16+hi*4+r, q = qi*16+la */
    f32x4 S[4][2];
    #pragma unroll
    for (int mf = 0; mf < 4; mf++)
      #pragma unroll
      for (int qi = 0; qi < 2; qi++) S[mf][qi] = f32x4{0.f,0.f,0.f,0.f};
    #pragma unroll
    for (int ks = 0; ks < 4; ks++) {
      bf16x8 kf[4];
      #pragma unroll
      for (int mf = 0; mf < 4; mf++) {
        int boff = (((mf*16 + la) << 8) + (ks << 6) + (hi << 4)) ^ ((la & 7) << 4);
        kf[mf] = *(const bf16x8*)((const char*)Ks[cur] + boff);
      }
      #pragma unroll
      for (int mf = 0; mf < 4; mf++)
        #pragma unroll
        for (int qi = 0; qi < 2; qi++)
          S[mf][qi] = __builtin_amdgcn_mfma_f32_16x16x32_bf16(kf[mf], qf[qi][ks], S[mf][qi], 0, 0, 0);
    }

    unsigned int pf[2][2][4];
    #pragma unroll
    for (int qi = 0; qi < 2; qi++) {
      float pm = S[0][qi][0];
      #pragma unroll
      for (int mf = 0; mf < 4; mf++)
        #pragma unroll
        for (int r = 0; r < 4; r++) pm = fmaxf(pm, S[mf][qi][r]);
      pm = fmaxf(pm, __shfl_xor(pm, 16));
      pm = fmaxf(pm, __shfl_xor(pm, 32));
      pm *= sc2;

      float mn;
      if (__all(pm <= mrun[qi] + 8.0f)) {
        mn = mrun[qi];
      } else {
        mn = fmaxf(mrun[qi], pm);
        float alpha = __builtin_amdgcn_exp2f(mrun[qi] - mn);
        mrun[qi] = mn;
        lrun[qi] *= alpha;
        #pragma unroll
        for (int r = 0; r < 4; r++) {
          float ar = __shfl(alpha, (lane & 48) | ((hi << 2) | r), 64);
          #pragma unroll
          for (int df = 0; df < 8; df++) o[qi][df][r] *= ar;
        }
      }

      float p[4][4]; float rs = 0.f;
      #pragma unroll
      for (int mf = 0; mf < 4; mf++)
        #pragma unroll
        for (int r = 0; r < 4; r++) {
          float e = __builtin_amdgcn_exp2f(fmaf(S[mf][qi][r], sc2, -mn));
          p[mf][r] = e; rs += e;
        }
      rs += __shfl_xor(rs, 16);
      rs += __shfl_xor(rs, 32);
      lrun[qi] += rs;

      unsigned int c[4][2];
      #pragma unroll
      for (int mf = 0; mf < 4; mf++) {
        c[mf][0] = cvtpk_bf16(p[mf][0], p[mf][1]);
        c[mf][1] = cvtpk_bf16(p[mf][2], p[mf][3]);
      }
      #pragma unroll
      for (int ks2 = 0; ks2 < 2; ks2++) {
        #pragma unroll
        for (int w = 0; w < 4; w++) {
          int src = la + 16*(2*(hi & 1) + (w >> 1));
          unsigned int t0 = __shfl(c[2*ks2    ][w & 1], src, 64);
          unsigned int t1 = __shfl(c[2*ks2 + 1][w & 1], src, 64);
          pf[qi][ks2][w] = (hi >> 1) ? t1 : t0;
        }
      }
    }

    #pragma unroll
    for (int ks2 = 0; ks2 < 2; ks2++) {
      #pragma unroll
      for (int df = 0; df < 8; df++) {
        int vrow = df*16 + la;
        int boff = ((vrow << 7) + (ks2 << 6) + (hi << 4)) ^ ((la & 7) << 4);
        bf16x8 vf = *(const bf16x8*)((const char*)VTs[cur] + boff);
        #pragma unroll
        for (int qi = 0; qi < 2; qi++) {
          u32x4 pw = {pf[qi][ks2][0], pf[qi][ks2][1], pf[qi][ks2][2], pf[qi][ks2][3]};
          o[qi][df] = __builtin_amdgcn_mfma_f32_16x16x32_bf16(
              __builtin_bit_cast(bf16x8, pw), vf, o[qi][df], 0, 0, 0);
        }
      }
    }
    __syncthreads();
  }

  unsigned short* Ob = O + (size_t)b * SEQ * D_MODEL + h * DH;
  #pragma unroll
  for (int qi = 0; qi < 2; qi++) {
    float linv[4];
    #pragma unroll
    for (int r = 0; r < 4; r++)
      linv[r] = 1.0f / __shfl(lrun[qi], (lane & 48) | ((hi << 2) | r), 64);
    #pragma unroll
    for (int df = 0; df < 8; df++)
      #pragma unroll
      for (int r = 0; r < 4; r++) {
        int srow = qrow + qi*16 + hi*4 + r;
        Ob[(size_t)srow * D_MODEL + df*16 + la] = f2bf(o[qi][df][r] * linv[r]);
      }
  }
}

/* ---------------- launcher ---------------- */
extern "C" void kernel_launch(void* const* d_in, const int* in_sizes, int n_in,
                              void* d_out, int out_size, void* d_ws, size_t ws_size,
                              hipStream_t stream) {
  const float* x  = (const float*)d_in[0];
  const float* wq = (const float*)d_in[1];
  const float* bq = (const float*)d_in[2];
  const float* wk = (const float*)d_in[3];
  const float* bk = (const float*)d_in[4];
  const float* wv = (const float*)d_in[5];
  const float* bv = (const float*)d_in[6];
  const float* wo = (const float*)d_in[7];
  const float* bo = (const float*)d_in[8];
  float* out = (float*)d_out;

  const size_t X = (size_t)MROWS * D_MODEL;   /* 8388608  */
  const size_t W = (size_t)D_MODEL * D_MODEL; /* 4194304  */

  unsigned short* ws  = (unsigned short*)d_ws;
  unsigned short* xb  = ws;
  unsigned short* wqb = xb  + X;   /* wqb,wkb,wvb,wob contiguous */
  unsigned short* wkb = wqb + W;
  unsigned short* wvb = wkb + W;
  unsigned short* wob = wvb + W;
  unsigned short* qb  = wob + W;
  unsigned short* kb  = qb  + X;
  unsigned short* vtg = kb  + X;
  unsigned short* ab  = vtg + X;

  cast_all<<<dim3(12288), 256, 0, stream>>>(x, wq, wk, wv, wo, xb, wqb);

  /* fused QKV: M=4096, N=6144, 256x192 tiles -> 16x32 = 512 blocks
     (2 exact CU-rounds at 1 block/CU) */
  gemm192<<<dim3(512), 512, 0, stream>>>(xb, wqb, bq, bk, bv, qb, kb, vtg);

  attn_fwd<<<dim3(512), 256, 0, stream>>>(qb, kb, vtg, ab);

  /* out-proj: M=4096, N=2048 -> 32x8 = 256 blocks (1 exact CU-round) */
  gemm256<<<dim3(256), 512, 0, stream>>>(ab, wob, bo, out, 1);
}

// Round 16
// 268.732 us; speedup vs baseline: 1.0342x; 1.0174x over previous
//
#include <hip/hip_runtime.h>

#define D_MODEL 2048
#define SEQ     2048
#define NB      2
#define NH      16
#define DH      128
#define MROWS   (NB*SEQ)   /* 4096 */
#define GK      2048       /* K dim of all GEMMs */
#define NT      (GK/64)    /* 32 K-tiles */

typedef __bf16 bf16x8 __attribute__((ext_vector_type(8)));
typedef float  f32x4  __attribute__((ext_vector_type(4)));
typedef unsigned short ushort8 __attribute__((ext_vector_type(8)));
typedef unsigned int   u32x4   __attribute__((ext_vector_type(4)));

__device__ __forceinline__ unsigned short f2bf(float f) {
  unsigned int u = __float_as_uint(f);
  u += 0x7FFFu + ((u >> 16) & 1u);
  return (unsigned short)(u >> 16);
}

__device__ __forceinline__ unsigned int cvtpk_bf16(float lo, float hi) {
  unsigned int r;
  asm("v_cvt_pk_bf16_f32 %0, %1, %2" : "=v"(r) : "v"(lo), "v"(hi));
  return r;
}

__device__ __forceinline__ void gload16(void* lds, const void* g) {
  __builtin_amdgcn_global_load_lds(
      (__attribute__((address_space(1))) void*)(g),
      (__attribute__((address_space(3))) void*)(lds), 16, 0, 0);
}

/* ---- fused cast: blocks 0-4095 = x (fp32->bf16), 4096-12287 = wq|wk|wv|wo */
__global__ __launch_bounds__(256) void cast_all(
    const float* __restrict__ x,
    const float* __restrict__ w0, const float* __restrict__ w1,
    const float* __restrict__ w2, const float* __restrict__ w3,
    unsigned short* __restrict__ xb, unsigned short* __restrict__ wb) {
  int gb = blockIdx.x;
  const float* src;
  unsigned short* dst;
  int i;
  if (gb < 4096) {
    src = x; dst = xb; i = gb * 256 + threadIdx.x;
  } else {
    int g2 = gb - 4096;
    int which = g2 >> 11;
    src = (which == 0) ? w0 : (which == 1) ? w1 : (which == 2) ? w2 : w3;
    dst = wb + (size_t)which * 4194304;
    i = (g2 & 2047) * 256 + threadIdx.x;
  }
  const float4* p = (const float4*)src;
  float4 a = p[2*i], b = p[2*i+1];
  ushort8 o;
  o[0]=f2bf(a.x); o[1]=f2bf(a.y); o[2]=f2bf(a.z); o[3]=f2bf(a.w);
  o[4]=f2bf(b.x); o[5]=f2bf(b.y); o[6]=f2bf(b.z); o[7]=f2bf(b.w);
  ((ushort8*)dst)[i] = o;
}

/* ---------------- QKV GEMM 256x192, BK=64, 8 waves (2Mx4N), wave-tile
   128x48, 2-slot LDS (112KB), zero-conflict XOR swizzle, bn-major XCD map,
   grid 512 = 2 exact CU-rounds.
   r16: TRUE counted-vmcnt pipeline (T4/m218) on the r15 4-phase skeleton.
   Staging units {B(3),A0(2),A1(2)} of tile t+1 issued in phases 1,2,3 of
   iter t; waits vmcnt(3) end-ph1 (retires A1(t)) and vmcnt(2) end-ph4
   (retires B,A0 of t+1) — every waited load is >=2 phases (~2000cyc) old,
   so the loop never stalls on memory. Tail iter drains with vmcnt(0).      */
__global__ __launch_bounds__(512, 2) void gemm192(
    const unsigned short* __restrict__ A,
    const unsigned short* __restrict__ B,
    const float* __restrict__ b0, const float* __restrict__ b1,
    const float* __restrict__ b2,
    unsigned short* __restrict__ qo, unsigned short* __restrict__ ko,
    unsigned short* __restrict__ vo)
{
  __shared__ char lds[2*57344];   /* slot: A 32KB [256][64] + B 24KB [192][64] */

  const int tid  = threadIdx.x;
  const int lane = tid & 63, wid = tid >> 6;
  const int la   = lane & 15, hi = lane >> 4;
  const int wm   = wid >> 2,  wn = wid & 3;

  const int xcd = (int)blockIdx.x & 7, ii = (int)blockIdx.x >> 3;
  const int bm  = ii >> 2;            /* 16 M-tiles, A-panel-sharing adjacent */
  const int bn  = xcd * 4 + (ii & 3); /* 4 B-panels per XCD (~3MB in L2)      */

  const unsigned short* Ab = A + (size_t)(bm*256) * GK;
  const unsigned short* Bb = B + (size_t)(bn*192) * GK;

  f32x4 acc[8][3];
  #pragma unroll
  for (int m = 0; m < 8; m++)
    #pragma unroll
    for (int n = 0; n < 3; n++) acc[m][n] = f32x4{0.f,0.f,0.f,0.f};

/* staging units: exact partition of the r12-proven STG index algebra */
#define STG_AJ(base_, kt, J0, J1) do {                                        \
    _Pragma("unroll")                                                         \
    for (int j = (J0); j < (J1); j++) {                                       \
      int idx = j*512 + tid;                                                  \
      int row = idx >> 3;                                                     \
      int c   = (idx & 7) << 4;                                               \
      gload16((base_) + idx*16,                                               \
              Ab + (size_t)row*GK + (kt)*64 + ((c ^ ((row&7)<<4)) >> 1));     \
    }                                                                         \
  } while (0)

#define STG_BJ(base_, kt, J0, J1) do {                                        \
    _Pragma("unroll")                                                         \
    for (int j = (J0); j < (J1); j++) {                                       \
      int idx = j*512 + tid;                                                  \
      int row = idx >> 3;                                                     \
      int c   = (idx & 7) << 4;                                               \
      gload16((base_) + 32768 + idx*16,                                       \
              Bb + (size_t)row*GK + (kt)*64 + ((c ^ ((row&7)<<4)) >> 1));     \
    }                                                                         \
  } while (0)

  /* prologue: stage tile 0 in steady-state unit order {B, A0, A1};
     wait B+A0 (leave A1 in flight), barrier */
  STG_BJ(lds, 0, 0, 3);
  STG_AJ(lds, 0, 0, 2);
  STG_AJ(lds, 0, 2, 4);
  asm volatile("s_waitcnt vmcnt(2)" ::: "memory");
  __builtin_amdgcn_s_barrier();

  const int xr = (la & 7) << 4;

  #pragma unroll 1
  for (int t = 0; t < NT; ++t) {
    const char* sa  = lds + (t&1)*57344;
    const char* sbp = sa + 32768;
    char* nb = lds + ((t+1)&1)*57344;
    const bool pf = (t + 1 < NT);

    bf16x8 bfr[3], aq[4];

    /* ---- phase 1: (ks0, B + A rows 0-3); issue STG_B(t+1) ---- */
    #pragma unroll
    for (int n = 0; n < 3; n++)
      bfr[n] = *(const bf16x8*)(sbp + (((wn*48 + n*16 + la)*128 + hi*16) ^ xr));
    #pragma unroll
    for (int m = 0; m < 4; m++)
      aq[m] = *(const bf16x8*)(sa + (((wm*128 + m*16 + la)*128 + hi*16) ^ xr));
    if (pf) STG_BJ(nb, t+1, 0, 3);
    asm volatile("s_waitcnt lgkmcnt(0)" ::: "memory");
    __builtin_amdgcn_sched_barrier(0);
    __builtin_amdgcn_s_setprio(1);
    #pragma unroll
    for (int m = 0; m < 4; m++)
      #pragma unroll
      for (int n = 0; n < 3; n++)
        acc[m][n] = __builtin_amdgcn_mfma_f32_16x16x32_bf16(aq[m], bfr[n], acc[m][n], 0, 0, 0);
    __builtin_amdgcn_s_setprio(0);
    /* retire A1(t) (issued 3 phases ago); B(t+1) stays in flight */
    if (pf) asm volatile("s_waitcnt vmcnt(3)" ::: "memory");
    else    asm volatile("s_waitcnt vmcnt(0)" ::: "memory");
    __builtin_amdgcn_s_barrier();

    /* ---- phase 2: (ks0, A rows 4-7), B-frags persist; STG_A0(t+1) ---- */
    #pragma unroll
    for (int m = 0; m < 4; m++)
      aq[m] = *(const bf16x8*)(sa + (((wm*128 + (m+4)*16 + la)*128 + hi*16) ^ xr));
    if (pf) STG_AJ(nb, t+1, 0, 2);
    asm volatile("s_waitcnt lgkmcnt(0)" ::: "memory");
    __builtin_amdgcn_sched_barrier(0);
    __builtin_amdgcn_s_setprio(1);
    #pragma unroll
    for (int m = 0; m < 4; m++)
      #pragma unroll
      for (int n = 0; n < 3; n++)
        acc[m+4][n] = __builtin_amdgcn_mfma_f32_16x16x32_bf16(aq[m], bfr[n], acc[m+4][n], 0, 0, 0);
    __builtin_amdgcn_s_setprio(0);
    __builtin_amdgcn_s_barrier();

    /* ---- phase 3: (ks1, B + A rows 0-3), resident; STG_A1(t+1) ---- */
    #pragma unroll
    for (int n = 0; n < 3; n++)
      bfr[n] = *(const bf16x8*)(sbp + (((wn*48 + n*16 + la)*128 + 64 + hi*16) ^ xr));
    #pragma unroll
    for (int m = 0; m < 4; m++)
      aq[m] = *(const bf16x8*)(sa + (((wm*128 + m*16 + la)*128 + 64 + hi*16) ^ xr));
    if (pf) STG_AJ(nb, t+1, 2, 4);
    asm volatile("s_waitcnt lgkmcnt(0)" ::: "memory");
    __builtin_amdgcn_sched_barrier(0);
    __builtin_amdgcn_s_setprio(1);
    #pragma unroll
    for (int m = 0; m < 4; m++)
      #pragma unroll
      for (int n = 0; n < 3; n++)
        acc[m][n] = __builtin_amdgcn_mfma_f32_16x16x32_bf16(aq[m], bfr[n], acc[m][n], 0, 0, 0);
    __builtin_amdgcn_s_setprio(0);
    __builtin_amdgcn_s_barrier();

    /* ---- phase 4: (ks1, A rows 4-7) ---- */
    #pragma unroll
    for (int m = 0; m < 4; m++)
      aq[m] = *(const bf16x8*)(sa + (((wm*128 + (m+4)*16 + la)*128 + 64 + hi*16) ^ xr));
    asm volatile("s_waitcnt lgkmcnt(0)" ::: "memory");
    __builtin_amdgcn_sched_barrier(0);
    __builtin_amdgcn_s_setprio(1);
    #pragma unroll
    for (int m = 0; m < 4; m++)
      #pragma unroll
      for (int n = 0; n < 3; n++)
        acc[m+4][n] = __builtin_amdgcn_mfma_f32_16x16x32_bf16(aq[m], bfr[n], acc[m+4][n], 0, 0, 0);
    __builtin_amdgcn_s_setprio(0);
    /* retire B(t+1)+A0(t+1) (issued 3 and 2 phases ago); A1(t+1) in flight */
    if (pf) asm volatile("s_waitcnt vmcnt(2)" ::: "memory");
    else    asm volatile("s_waitcnt vmcnt(0)" ::: "memory");
    __builtin_amdgcn_s_barrier();   /* also fences slot-t reads before restage */
  }
#undef STG_AJ
#undef STG_BJ

  /* epilogue: mat per n-frag (192-tiles straddle q/k/v boundaries) */
  const int row0 = bm*256 + wm*128;
  const int col0 = bn*192 + wn*48;
  #pragma unroll
  for (int n = 0; n < 3; n++) {
    int col = col0 + n*16 + la;
    int mat = col >> 11;          /* 0=q 1=k 2=v, uniform across the wave */
    int c   = col & 2047;
    int h   = c >> 7, d = c & 127;
    const float* bp = (mat == 0) ? b0 : (mat == 1) ? b1 : b2;
    float bv = bp[c];
    #pragma unroll
    for (int m = 0; m < 8; m++)
      #pragma unroll
      for (int r = 0; r < 4; r++) {
        int row = row0 + m*16 + hi*4 + r;
        int bb  = row >> 11, s = row & (SEQ-1);
        unsigned short val = f2bf(acc[m][n][r] + bv);
        if (mat == 0) {
          qo[((size_t)(bb*NH + h)*SEQ + s)*DH + d] = val;
        } else if (mat == 1) {
          size_t base = ((size_t)(bb*NH + h)*SEQ + (size_t)(s >> 6)*64)*DH;
          int boff = (((s & 63) << 8) + (d << 1)) ^ ((s & 7) << 4);
          ko[base + (boff >> 1)] = val;
        } else {
          size_t base = ((size_t)(bb*NH + h)*SEQ + (size_t)(s >> 6)*64)*DH;
          int boff = ((d << 7) + ((s & 63) << 1)) ^ ((d & 7) << 4);
          vo[base + (boff >> 1)] = val;
        }
      }
  }
}

/* ---------------- out-proj GEMM 128x256 (round-6 proven, mode-1 use) ---- */
__global__ __launch_bounds__(512, 2) void gemm256(
    const unsigned short* __restrict__ A,
    const unsigned short* __restrict__ B,
    const float* __restrict__ b0,
    float* __restrict__ fo,
    int nbnx)
{
  __shared__ char lds[3*49152];

  const int tid  = threadIdx.x;
  const int lane = tid & 63, wid = tid >> 6;
  const int la   = lane & 15, hi = lane >> 4;
  const int wm   = wid >> 2,  wn = wid & 3;

  const int xcd = (int)blockIdx.x & 7, ii = (int)blockIdx.x >> 3;
  const int bm  = ii / nbnx;
  const int bn  = xcd * nbnx + ii % nbnx;

  const unsigned short* Ab = A + (size_t)(bm*128) * GK;
  const unsigned short* Bb = B + (size_t)(bn*256) * GK;

  f32x4 acc[4][4];
  #pragma unroll
  for (int m = 0; m < 4; m++)
    #pragma unroll
    for (int n = 0; n < 4; n++) acc[m][n] = f32x4{0.f,0.f,0.f,0.f};

#define STAGE_A(slot, kt) do {                                                \
    int sb_ = (slot) * 49152;                                                 \
    _Pragma("unroll")                                                         \
    for (int j = 0; j < 2; j++) {                                             \
      int idx = j*512 + tid;                                                  \
      int row = idx >> 3;                                                     \
      int c   = (idx & 7) << 4;                                               \
      gload16(lds + sb_ + idx*16,                                             \
              Ab + (size_t)row*GK + (kt)*64 + ((c ^ ((row&7)<<4)) >> 1));     \
    }                                                                         \
  } while (0)

#define STAGE_B(slot, kt) do {                                                \
    int sb_ = (slot) * 49152;                                                 \
    _Pragma("unroll")                                                         \
    for (int j = 0; j < 4; j++) {                                             \
      int idx = j*512 + tid;                                                  \
      int row = idx >> 3;                                                     \
      int c   = (idx & 7) << 4;                                               \
      gload16(lds + sb_ + 16384 + idx*16,                                     \
              Bb + (size_t)row*GK + (kt)*64 + ((c ^ ((row&7)<<4)) >> 1));     \
    }                                                                         \
  } while (0)

  STAGE_A(0, 0); STAGE_B(0, 0);
  STAGE_A(1, 1); STAGE_B(1, 1);

  int cs = 0, ps = 2;
  const int xr = (la & 7) << 4;

  #pragma unroll 1
  for (int t = 0; t < NT; ++t) {
    if (t + 1 < NT) asm volatile("s_waitcnt vmcnt(6)" ::: "memory");
    else            asm volatile("s_waitcnt vmcnt(0)" ::: "memory");
    __builtin_amdgcn_s_barrier();

    const char* sa  = lds + cs*49152;
    const char* sbp = sa + 16384;

    bf16x8 bfr[4][2], aA[2][2];
    #pragma unroll
    for (int n = 0; n < 4; n++)
      #pragma unroll
      for (int ks = 0; ks < 2; ks++)
        bfr[n][ks] = *(const bf16x8*)(sbp + (((wn*64 + n*16 + la)*128 + ks*64 + hi*16) ^ xr));
    #pragma unroll
    for (int m = 0; m < 2; m++)
      #pragma unroll
      for (int ks = 0; ks < 2; ks++)
        aA[m][ks] = *(const bf16x8*)(sa + (((wm*64 + m*16 + la)*128 + ks*64 + hi*16) ^ xr));

    if (t + 2 < NT) STAGE_A(ps, t + 2);

    asm volatile("s_waitcnt lgkmcnt(0)" ::: "memory");
    __builtin_amdgcn_sched_barrier(0);
    __builtin_amdgcn_s_setprio(1);
    #pragma unroll
    for (int m = 0; m < 2; m++)
      #pragma unroll
      for (int n = 0; n < 4; n++)
        #pragma unroll
        for (int ks = 0; ks < 2; ks++)
          acc[m][n] = __builtin_amdgcn_mfma_f32_16x16x32_bf16(aA[m][ks], bfr[n][ks], acc[m][n], 0, 0, 0);
    __builtin_amdgcn_s_setprio(0);
    __builtin_amdgcn_s_barrier();

    bf16x8 aB[2][2];
    #pragma unroll
    for (int m = 0; m < 2; m++)
      #pragma unroll
      for (int ks = 0; ks < 2; ks++)
        aB[m][ks] = *(const bf16x8*)(sa + (((wm*64 + (m+2)*16 + la)*128 + ks*64 + hi*16) ^ xr));

    if (t + 2 < NT) STAGE_B(ps, t + 2);

    asm volatile("s_waitcnt lgkmcnt(0)" ::: "memory");
    __builtin_amdgcn_sched_barrier(0);
    __builtin_amdgcn_s_setprio(1);
    #pragma unroll
    for (int m = 0; m < 2; m++)
      #pragma unroll
      for (int n = 0; n < 4; n++)
        #pragma unroll
        for (int ks = 0; ks < 2; ks++)
          acc[m+2][n] = __builtin_amdgcn_mfma_f32_16x16x32_bf16(aB[m][ks], bfr[n][ks], acc[m+2][n], 0, 0, 0);
    __builtin_amdgcn_s_setprio(0);

    cs = cs + 1; if (cs == 3) cs = 0;
    ps = ps + 1; if (ps == 3) ps = 0;
  }
#undef STAGE_A
#undef STAGE_B

  const int row0 = bm*128 + wm*64;
  const int col0 = bn*256 + wn*64;
  #pragma unroll
  for (int n = 0; n < 4; n++) {
    int col = col0 + n*16 + la;
    float bv = b0[col];
    #pragma unroll
    for (int m = 0; m < 4; m++)
      #pragma unroll
      for (int r = 0; r < 4; r++) {
        int row = row0 + m*16 + hi*4 + r;
        fo[(size_t)row*D_MODEL + col] = acc[m][n][r] + bv;
      }
  }
}

/* ---------------- flash attention fwd (round-10 proven: T13 defer-max +
   exp2-domain softmax) ---------------- */
__global__ __launch_bounds__(256, 2) void attn_fwd(
    const unsigned short* __restrict__ Q,
    const unsigned short* __restrict__ Kg,
    const unsigned short* __restrict__ VTg,
    unsigned short* __restrict__ O)
{
  __shared__ unsigned short Ks [2][64*128];
  __shared__ unsigned short VTs[2][128*64];

  const int tid  = threadIdx.x;
  const int lane = tid & 63, wid = tid >> 6;
  const int la   = lane & 15, hi = lane >> 4;
  const int swz  = ((int)(blockIdx.x & 7) << 6) + ((int)blockIdx.x >> 3);
  const int bh   = swz >> 4;
  const int q0   = (swz & 15) << 7;
  const int b    = bh >> 4, h = bh & 15;

  const unsigned short* Qh = Q   + (size_t)bh * SEQ * DH;
  const unsigned short* Kh = Kg  + (size_t)bh * SEQ * DH;
  const unsigned short* Vh = VTg + (size_t)bh * SEQ * DH;

  const int qrow = q0 + wid * 32;

  bf16x8 qf[2][4];
  #pragma unroll
  for (int qi = 0; qi < 2; qi++)
    #pragma unroll
    for (int ks = 0; ks < 4; ks++)
      qf[qi][ks] = *(const bf16x8*)(Qh + (size_t)(qrow + qi*16 + la)*DH + ks*32 + hi*8);

  f32x4 o[2][8];
  float mrun[2], lrun[2];
  #pragma unroll
  for (int qi = 0; qi < 2; qi++) {
    #pragma unroll
    for (int df = 0; df < 8; df++) o[qi][df] = f32x4{0.f,0.f,0.f,0.f};
    mrun[qi] = -1e30f; lrun[qi] = 0.f;
  }

  #pragma unroll
  for (int i = 0; i < 4; i++) {
    int off = i*4096 + tid*16;
    gload16((char*)Ks[0]  + off, (const char*)Kh + off);
    gload16((char*)VTs[0] + off, (const char*)Vh + off);
  }
  __syncthreads();

  /* log2-domain scale: log2(e)/sqrt(128) */
  const float sc2 = 0.1275424483f;

  #pragma unroll 1
  for (int t = 0; t < SEQ/64; ++t) {
    const int cur = t & 1;

    if (t + 1 < SEQ/64) {
      const char* kt = (const char*)(Kh + (size_t)(t+1)*(64*DH));
      const char* vt = (const char*)(Vh + (size_t)(t+1)*(64*DH));
      #pragma unroll
      for (int i = 0; i < 4; i++) {
        int off = i*4096 + tid*16;
        gload16((char*)Ks[cur^1]  + off, kt + off);
        gload16((char*)VTs[cur^1] + off, vt + off);
      }
    }

    /* S^T[kv][q] = K Q^T : S[mf][qi], kv = mf*16+hi*4+r, q = qi*16+la */
    f32x4 S[4][2];
    #pragma unroll
    for (int mf = 0; mf < 4; mf++)
      #pragma unroll
      for (int qi = 0; qi < 2; qi++) S[mf][qi] = f32x4{0.f,0.f,0.f,0.f};
    #pragma unroll
    for (int ks = 0; ks < 4; ks++) {
      bf16x8 kf[4];
      #pragma unroll
      for (int mf = 0; mf < 4; mf++) {
        int boff = (((mf*16 + la) << 8) + (ks << 6) + (hi << 4)) ^ ((la & 7) << 4);
        kf[mf] = *(const bf16x8*)((const char*)Ks[cur] + boff);
      }
      #pragma unroll
      for (int mf = 0; mf < 4; mf++)
        #pragma unroll
        for (int qi = 0; qi < 2; qi++)
          S[mf][qi] = __builtin_amdgcn_mfma_f32_16x16x32_bf16(kf[mf], qf[qi][ks], S[mf][qi], 0, 0, 0);
    }

    unsigned int pf[2][2][4];
    #pragma unroll
    for (int qi = 0; qi < 2; qi++) {
      float pm = S[0][qi][0];
      #pragma unroll
      for (int mf = 0; mf < 4; mf++)
        #pragma unroll
        for (int r = 0; r < 4; r++) pm = fmaxf(pm, S[mf][qi][r]);
      pm = fmaxf(pm, __shfl_xor(pm, 16));
      pm = fmaxf(pm, __shfl_xor(pm, 32));
      pm *= sc2;

      float mn;
      if (__all(pm <= mrun[qi] + 8.0f)) {
        mn = mrun[qi];
      } else {
        mn = fmaxf(mrun[qi], pm);
        float alpha = __builtin_amdgcn_exp2f(mrun[qi] - mn);
        mrun[qi] = mn;
        lrun[qi] *= alpha;
        #pragma unroll
        for (int r = 0; r < 4; r++) {
          float ar = __shfl(alpha, (lane & 48) | ((hi << 2) | r), 64);
          #pragma unroll
          for (int df = 0; df < 8; df++) o[qi][df][r] *= ar;
        }
      }

      float p[4][4]; float rs = 0.f;
      #pragma unroll
      for (int mf = 0; mf < 4; mf++)
        #pragma unroll
        for (int r = 0; r < 4; r++) {
          float e = __builtin_amdgcn_exp2f(fmaf(S[mf][qi][r], sc2, -mn));
          p[mf][r] = e; rs += e;
        }
      rs += __shfl_xor(rs, 16);
      rs += __shfl_xor(rs, 32);
      lrun[qi] += rs;

      unsigned int c[4][2];
      #pragma unroll
      for (int mf = 0; mf < 4; mf++) {
        c[mf][0] = cvtpk_bf16(p[mf][0], p[mf][1]);
        c[mf][1] = cvtpk_bf16(p[mf][2], p[mf][3]);
      }
      #pragma unroll
      for (int ks2 = 0; ks2 < 2; ks2++) {
        #pragma unroll
        for (int w = 0; w < 4; w++) {
          int src = la + 16*(2*(hi & 1) + (w >> 1));
          unsigned int t0 = __shfl(c[2*ks2    ][w & 1], src, 64);
          unsigned int t1 = __shfl(c[2*ks2 + 1][w & 1], src, 64);
          pf[qi][ks2][w] = (hi >> 1) ? t1 : t0;
        }
      }
    }

    #pragma unroll
    for (int ks2 = 0; ks2 < 2; ks2++) {
      #pragma unroll
      for (int df = 0; df < 8; df++) {
        int vrow = df*16 + la;
        int boff = ((vrow << 7) + (ks2 << 6) + (hi << 4)) ^ ((la & 7) << 4);
        bf16x8 vf = *(const bf16x8*)((const char*)VTs[cur] + boff);
        #pragma unroll
        for (int qi = 0; qi < 2; qi++) {
          u32x4 pw = {pf[qi][ks2][0], pf[qi][ks2][1], pf[qi][ks2][2], pf[qi][ks2][3]};
          o[qi][df] = __builtin_amdgcn_mfma_f32_16x16x32_bf16(
              __builtin_bit_cast(bf16x8, pw), vf, o[qi][df], 0, 0, 0);
        }
      }
    }
    __syncthreads();
  }

  unsigned short* Ob = O + (size_t)b * SEQ * D_MODEL + h * DH;
  #pragma unroll
  for (int qi = 0; qi < 2; qi++) {
    float linv[4];
    #pragma unroll
    for (int r = 0; r < 4; r++)
      linv[r] = 1.0f / __shfl(lrun[qi], (lane & 48) | ((hi << 2) | r), 64);
    #pragma unroll
    for (int df = 0; df < 8; df++)
      #pragma unroll
      for (int r = 0; r < 4; r++) {
        int srow = qrow + qi*16 + hi*4 + r;
        Ob[(size_t)srow * D_MODEL + df*16 + la] = f2bf(o[qi][df][r] * linv[r]);
      }
  }
}

/* ---------------- launcher ---------------- */
extern "C" void kernel_launch(void* const* d_in, const int* in_sizes, int n_in,
                              void* d_out, int out_size, void* d_ws, size_t ws_size,
                              hipStream_t stream) {
  const float* x  = (const float*)d_in[0];
  const float* wq = (const float*)d_in[1];
  const float* bq = (const float*)d_in[2];
  const float* wk = (const float*)d_in[3];
  const float* bk = (const float*)d_in[4];
  const float* wv = (const float*)d_in[5];
  const float* bv = (const float*)d_in[6];
  const float* wo = (const float*)d_in[7];
  const float* bo = (const float*)d_in[8];
  float* out = (float*)d_out;

  const size_t X = (size_t)MROWS * D_MODEL;   /* 8388608  */
  const size_t W = (size_t)D_MODEL * D_MODEL; /* 4194304  */

  unsigned short* ws  = (unsigned short*)d_ws;
  unsigned short* xb  = ws;
  unsigned short* wqb = xb  + X;   /* wqb,wkb,wvb,wob contiguous */
  unsigned short* wkb = wqb + W;
  unsigned short* wvb = wkb + W;
  unsigned short* wob = wvb + W;
  unsigned short* qb  = wob + W;
  unsigned short* kb  = qb  + X;
  unsigned short* vtg = kb  + X;
  unsigned short* ab  = vtg + X;

  cast_all<<<dim3(12288), 256, 0, stream>>>(x, wq, wk, wv, wo, xb, wqb);

  /* fused QKV: M=4096, N=6144, 256x192 tiles -> 16x32 = 512 blocks
     (2 exact CU-rounds at 1 block/CU) */
  gemm192<<<dim3(512), 512, 0, stream>>>(xb, wqb, bq, bk, bv, qb, kb, vtg);

  attn_fwd<<<dim3(512), 256, 0, stream>>>(qb, kb, vtg, ab);

  /* out-proj: M=4096, N=2048 -> 32x8 = 256 blocks (1 exact CU-round) */
  gemm256<<<dim3(256), 512, 0, stream>>>(ab, wob, bo, out, 1);
}

// Round 17
// 268.099 us; speedup vs baseline: 1.0367x; 1.0024x over previous
//
#include <hip/hip_runtime.h>

#define D_MODEL 2048
#define SEQ     2048
#define NB      2
#define NH      16
#define DH      128
#define MROWS   (NB*SEQ)   /* 4096 */
#define GK      2048       /* K dim of all GEMMs */
#define NT      (GK/64)    /* 32 K-tiles */

typedef __bf16 bf16x8 __attribute__((ext_vector_type(8)));
typedef float  f32x4  __attribute__((ext_vector_type(4)));
typedef unsigned short ushort8 __attribute__((ext_vector_type(8)));
typedef unsigned int   u32x4   __attribute__((ext_vector_type(4)));

__device__ __forceinline__ unsigned short f2bf(float f) {
  unsigned int u = __float_as_uint(f);
  u += 0x7FFFu + ((u >> 16) & 1u);
  return (unsigned short)(u >> 16);
}

__device__ __forceinline__ unsigned int cvtpk_bf16(float lo, float hi) {
  unsigned int r;
  asm("v_cvt_pk_bf16_f32 %0, %1, %2" : "=v"(r) : "v"(lo), "v"(hi));
  return r;
}

__device__ __forceinline__ void gload16(void* lds, const void* g) {
  __builtin_amdgcn_global_load_lds(
      (__attribute__((address_space(1))) void*)(g),
      (__attribute__((address_space(3))) void*)(lds), 16, 0, 0);
}

/* ---- fused cast: blocks 0-4095 = x (fp32->bf16), 4096-12287 = wq|wk|wv|wo */
__global__ __launch_bounds__(256) void cast_all(
    const float* __restrict__ x,
    const float* __restrict__ w0, const float* __restrict__ w1,
    const float* __restrict__ w2, const float* __restrict__ w3,
    unsigned short* __restrict__ xb, unsigned short* __restrict__ wb) {
  int gb = blockIdx.x;
  const float* src;
  unsigned short* dst;
  int i;
  if (gb < 4096) {
    src = x; dst = xb; i = gb * 256 + threadIdx.x;
  } else {
    int g2 = gb - 4096;
    int which = g2 >> 11;
    src = (which == 0) ? w0 : (which == 1) ? w1 : (which == 2) ? w2 : w3;
    dst = wb + (size_t)which * 4194304;
    i = (g2 & 2047) * 256 + threadIdx.x;
  }
  const float4* p = (const float4*)src;
  float4 a = p[2*i], b = p[2*i+1];
  ushort8 o;
  o[0]=f2bf(a.x); o[1]=f2bf(a.y); o[2]=f2bf(a.z); o[3]=f2bf(a.w);
  o[4]=f2bf(b.x); o[5]=f2bf(b.y); o[6]=f2bf(b.z); o[7]=f2bf(b.w);
  ((ushort8*)dst)[i] = o;
}

/* ---------------- QKV GEMM 256x192, BK=64, 8 waves (2Mx4N), wave-tile
   128x48, 2-slot LDS (112KB), zero-conflict XOR swizzle, bn-major XCD map,
   grid 512 = 2 exact CU-rounds.
   r17: r16's counted-vmcnt pipeline with RACE-FIXED staging units. A-units
   partitioned by PHASE COVERAGE: A_first = j{0,2} (rows 0-63,128-191 = the
   ph1/ph3 reads of BOTH wm groups), A_second = j{1,3} (rows 64-127,192-255
   = ph2/ph4 reads). Ledger: prologue vmcnt(2) leaves A_second in flight
   (not read until ph2, after end-ph1 vmcnt(3) retires it); end-ph4 vmcnt(2)
   retires B+A_first of t+1 before ph1 reads them. Every read covered by a
   retired unit; every waited load >=2 phases old.                          */
__global__ __launch_bounds__(512, 2) void gemm192(
    const unsigned short* __restrict__ A,
    const unsigned short* __restrict__ B,
    const float* __restrict__ b0, const float* __restrict__ b1,
    const float* __restrict__ b2,
    unsigned short* __restrict__ qo, unsigned short* __restrict__ ko,
    unsigned short* __restrict__ vo)
{
  __shared__ char lds[2*57344];   /* slot: A 32KB [256][64] + B 24KB [192][64] */

  const int tid  = threadIdx.x;
  const int lane = tid & 63, wid = tid >> 6;
  const int la   = lane & 15, hi = lane >> 4;
  const int wm   = wid >> 2,  wn = wid & 3;

  const int xcd = (int)blockIdx.x & 7, ii = (int)blockIdx.x >> 3;
  const int bm  = ii >> 2;            /* 16 M-tiles, A-panel-sharing adjacent */
  const int bn  = xcd * 4 + (ii & 3); /* 4 B-panels per XCD (~3MB in L2)      */

  const unsigned short* Ab = A + (size_t)(bm*256) * GK;
  const unsigned short* Bb = B + (size_t)(bn*192) * GK;

  f32x4 acc[8][3];
  #pragma unroll
  for (int m = 0; m < 8; m++)
    #pragma unroll
    for (int n = 0; n < 3; n++) acc[m][n] = f32x4{0.f,0.f,0.f,0.f};

/* single-j staging unit (512 threads x 16B = 128 rows per j) */
#define STG_A1J(base_, kt, J) do {                                            \
    int idx = (J)*512 + tid;                                                  \
    int row = idx >> 3;                                                       \
    int c   = (idx & 7) << 4;                                                 \
    gload16((base_) + idx*16,                                                 \
            Ab + (size_t)row*GK + (kt)*64 + ((c ^ ((row&7)<<4)) >> 1));       \
  } while (0)

#define STG_BJ(base_, kt, J0, J1) do {                                        \
    _Pragma("unroll")                                                         \
    for (int j = (J0); j < (J1); j++) {                                       \
      int idx = j*512 + tid;                                                  \
      int row = idx >> 3;                                                     \
      int c   = (idx & 7) << 4;                                               \
      gload16((base_) + 32768 + idx*16,                                       \
              Bb + (size_t)row*GK + (kt)*64 + ((c ^ ((row&7)<<4)) >> 1));     \
    }                                                                         \
  } while (0)

  /* prologue: stage tile 0 in unit order {B, A_first, A_second};
     vmcnt(2) retires B+A_first, leaves A_second in flight */
  STG_BJ(lds, 0, 0, 3);
  STG_A1J(lds, 0, 0); STG_A1J(lds, 0, 2);   /* A_first: rows 0-63,128-191 */
  STG_A1J(lds, 0, 1); STG_A1J(lds, 0, 3);   /* A_second: rows 64-127,192-255 */
  asm volatile("s_waitcnt vmcnt(2)" ::: "memory");
  __builtin_amdgcn_s_barrier();

  const int xr = (la & 7) << 4;

  #pragma unroll 1
  for (int t = 0; t < NT; ++t) {
    const char* sa  = lds + (t&1)*57344;
    const char* sbp = sa + 32768;
    char* nb = lds + ((t+1)&1)*57344;
    const bool pf = (t + 1 < NT);

    bf16x8 bfr[3], aq[4];

    /* ---- phase 1: (ks0, B + A rows m0-3 = A_first coverage);
            issue STG_B(t+1) ---- */
    #pragma unroll
    for (int n = 0; n < 3; n++)
      bfr[n] = *(const bf16x8*)(sbp + (((wn*48 + n*16 + la)*128 + hi*16) ^ xr));
    #pragma unroll
    for (int m = 0; m < 4; m++)
      aq[m] = *(const bf16x8*)(sa + (((wm*128 + m*16 + la)*128 + hi*16) ^ xr));
    if (pf) STG_BJ(nb, t+1, 0, 3);
    asm volatile("s_waitcnt lgkmcnt(0)" ::: "memory");
    __builtin_amdgcn_sched_barrier(0);
    __builtin_amdgcn_s_setprio(1);
    #pragma unroll
    for (int m = 0; m < 4; m++)
      #pragma unroll
      for (int n = 0; n < 3; n++)
        acc[m][n] = __builtin_amdgcn_mfma_f32_16x16x32_bf16(aq[m], bfr[n], acc[m][n], 0, 0, 0);
    __builtin_amdgcn_s_setprio(0);
    /* retire A_second(t) (issued 3 phases ago); B(t+1) stays in flight */
    if (pf) asm volatile("s_waitcnt vmcnt(3)" ::: "memory");
    else    asm volatile("s_waitcnt vmcnt(0)" ::: "memory");
    __builtin_amdgcn_s_barrier();

    /* ---- phase 2: (ks0, A rows m4-7 = A_second coverage), B persists;
            issue STG_A_first(t+1) ---- */
    #pragma unroll
    for (int m = 0; m < 4; m++)
      aq[m] = *(const bf16x8*)(sa + (((wm*128 + (m+4)*16 + la)*128 + hi*16) ^ xr));
    if (pf) { STG_A1J(nb, t+1, 0); STG_A1J(nb, t+1, 2); }
    asm volatile("s_waitcnt lgkmcnt(0)" ::: "memory");
    __builtin_amdgcn_sched_barrier(0);
    __builtin_amdgcn_s_setprio(1);
    #pragma unroll
    for (int m = 0; m < 4; m++)
      #pragma unroll
      for (int n = 0; n < 3; n++)
        acc[m+4][n] = __builtin_amdgcn_mfma_f32_16x16x32_bf16(aq[m], bfr[n], acc[m+4][n], 0, 0, 0);
    __builtin_amdgcn_s_setprio(0);
    __builtin_amdgcn_s_barrier();

    /* ---- phase 3: (ks1, B + A rows m0-3); issue STG_A_second(t+1) ---- */
    #pragma unroll
    for (int n = 0; n < 3; n++)
      bfr[n] = *(const bf16x8*)(sbp + (((wn*48 + n*16 + la)*128 + 64 + hi*16) ^ xr));
    #pragma unroll
    for (int m = 0; m < 4; m++)
      aq[m] = *(const bf16x8*)(sa + (((wm*128 + m*16 + la)*128 + 64 + hi*16) ^ xr));
    if (pf) { STG_A1J(nb, t+1, 1); STG_A1J(nb, t+1, 3); }
    asm volatile("s_waitcnt lgkmcnt(0)" ::: "memory");
    __builtin_amdgcn_sched_barrier(0);
    __builtin_amdgcn_s_setprio(1);
    #pragma unroll
    for (int m = 0; m < 4; m++)
      #pragma unroll
      for (int n = 0; n < 3; n++)
        acc[m][n] = __builtin_amdgcn_mfma_f32_16x16x32_bf16(aq[m], bfr[n], acc[m][n], 0, 0, 0);
    __builtin_amdgcn_s_setprio(0);
    __builtin_amdgcn_s_barrier();

    /* ---- phase 4: (ks1, A rows m4-7) ---- */
    #pragma unroll
    for (int m = 0; m < 4; m++)
      aq[m] = *(const bf16x8*)(sa + (((wm*128 + (m+4)*16 + la)*128 + 64 + hi*16) ^ xr));
    asm volatile("s_waitcnt lgkmcnt(0)" ::: "memory");
    __builtin_amdgcn_sched_barrier(0);
    __builtin_amdgcn_s_setprio(1);
    #pragma unroll
    for (int m = 0; m < 4; m++)
      #pragma unroll
      for (int n = 0; n < 3; n++)
        acc[m+4][n] = __builtin_amdgcn_mfma_f32_16x16x32_bf16(aq[m], bfr[n], acc[m+4][n], 0, 0, 0);
    __builtin_amdgcn_s_setprio(0);
    /* retire B(t+1)+A_first(t+1); A_second(t+1) stays in flight */
    if (pf) asm volatile("s_waitcnt vmcnt(2)" ::: "memory");
    else    asm volatile("s_waitcnt vmcnt(0)" ::: "memory");
    __builtin_amdgcn_s_barrier();   /* also fences slot-t reads before restage */
  }
#undef STG_A1J
#undef STG_BJ

  /* epilogue: mat per n-frag (192-tiles straddle q/k/v boundaries) */
  const int row0 = bm*256 + wm*128;
  const int col0 = bn*192 + wn*48;
  #pragma unroll
  for (int n = 0; n < 3; n++) {
    int col = col0 + n*16 + la;
    int mat = col >> 11;          /* 0=q 1=k 2=v, uniform across the wave */
    int c   = col & 2047;
    int h   = c >> 7, d = c & 127;
    const float* bp = (mat == 0) ? b0 : (mat == 1) ? b1 : b2;
    float bv = bp[c];
    #pragma unroll
    for (int m = 0; m < 8; m++)
      #pragma unroll
      for (int r = 0; r < 4; r++) {
        int row = row0 + m*16 + hi*4 + r;
        int bb  = row >> 11, s = row & (SEQ-1);
        unsigned short val = f2bf(acc[m][n][r] + bv);
        if (mat == 0) {
          qo[((size_t)(bb*NH + h)*SEQ + s)*DH + d] = val;
        } else if (mat == 1) {
          size_t base = ((size_t)(bb*NH + h)*SEQ + (size_t)(s >> 6)*64)*DH;
          int boff = (((s & 63) << 8) + (d << 1)) ^ ((s & 7) << 4);
          ko[base + (boff >> 1)] = val;
        } else {
          size_t base = ((size_t)(bb*NH + h)*SEQ + (size_t)(s >> 6)*64)*DH;
          int boff = ((d << 7) + ((s & 63) << 1)) ^ ((d & 7) << 4);
          vo[base + (boff >> 1)] = val;
        }
      }
  }
}

/* ---------------- out-proj GEMM 128x256 (round-6 proven, mode-1 use) ---- */
__global__ __launch_bounds__(512, 2) void gemm256(
    const unsigned short* __restrict__ A,
    const unsigned short* __restrict__ B,
    const float* __restrict__ b0,
    float* __restrict__ fo,
    int nbnx)
{
  __shared__ char lds[3*49152];

  const int tid  = threadIdx.x;
  const int lane = tid & 63, wid = tid >> 6;
  const int la   = lane & 15, hi = lane >> 4;
  const int wm   = wid >> 2,  wn = wid & 3;

  const int xcd = (int)blockIdx.x & 7, ii = (int)blockIdx.x >> 3;
  const int bm  = ii / nbnx;
  const int bn  = xcd * nbnx + ii % nbnx;

  const unsigned short* Ab = A + (size_t)(bm*128) * GK;
  const unsigned short* Bb = B + (size_t)(bn*256) * GK;

  f32x4 acc[4][4];
  #pragma unroll
  for (int m = 0; m < 4; m++)
    #pragma unroll
    for (int n = 0; n < 4; n++) acc[m][n] = f32x4{0.f,0.f,0.f,0.f};

#define STAGE_A(slot, kt) do {                                                \
    int sb_ = (slot) * 49152;                                                 \
    _Pragma("unroll")                                                         \
    for (int j = 0; j < 2; j++) {                                             \
      int idx = j*512 + tid;                                                  \
      int row = idx >> 3;                                                     \
      int c   = (idx & 7) << 4;                                               \
      gload16(lds + sb_ + idx*16,                                             \
              Ab + (size_t)row*GK + (kt)*64 + ((c ^ ((row&7)<<4)) >> 1));     \
    }                                                                         \
  } while (0)

#define STAGE_B(slot, kt) do {                                                \
    int sb_ = (slot) * 49152;                                                 \
    _Pragma("unroll")                                                         \
    for (int j = 0; j < 4; j++) {                                             \
      int idx = j*512 + tid;                                                  \
      int row = idx >> 3;                                                     \
      int c   = (idx & 7) << 4;                                               \
      gload16(lds + sb_ + 16384 + idx*16,                                     \
              Bb + (size_t)row*GK + (kt)*64 + ((c ^ ((row&7)<<4)) >> 1));     \
    }                                                                         \
  } while (0)

  STAGE_A(0, 0); STAGE_B(0, 0);
  STAGE_A(1, 1); STAGE_B(1, 1);

  int cs = 0, ps = 2;
  const int xr = (la & 7) << 4;

  #pragma unroll 1
  for (int t = 0; t < NT; ++t) {
    if (t + 1 < NT) asm volatile("s_waitcnt vmcnt(6)" ::: "memory");
    else            asm volatile("s_waitcnt vmcnt(0)" ::: "memory");
    __builtin_amdgcn_s_barrier();

    const char* sa  = lds + cs*49152;
    const char* sbp = sa + 16384;

    bf16x8 bfr[4][2], aA[2][2];
    #pragma unroll
    for (int n = 0; n < 4; n++)
      #pragma unroll
      for (int ks = 0; ks < 2; ks++)
        bfr[n][ks] = *(const bf16x8*)(sbp + (((wn*64 + n*16 + la)*128 + ks*64 + hi*16) ^ xr));
    #pragma unroll
    for (int m = 0; m < 2; m++)
      #pragma unroll
      for (int ks = 0; ks < 2; ks++)
        aA[m][ks] = *(const bf16x8*)(sa + (((wm*64 + m*16 + la)*128 + ks*64 + hi*16) ^ xr));

    if (t + 2 < NT) STAGE_A(ps, t + 2);

    asm volatile("s_waitcnt lgkmcnt(0)" ::: "memory");
    __builtin_amdgcn_sched_barrier(0);
    __builtin_amdgcn_s_setprio(1);
    #pragma unroll
    for (int m = 0; m < 2; m++)
      #pragma unroll
      for (int n = 0; n < 4; n++)
        #pragma unroll
        for (int ks = 0; ks < 2; ks++)
          acc[m][n] = __builtin_amdgcn_mfma_f32_16x16x32_bf16(aA[m][ks], bfr[n][ks], acc[m][n], 0, 0, 0);
    __builtin_amdgcn_s_setprio(0);
    __builtin_amdgcn_s_barrier();

    bf16x8 aB[2][2];
    #pragma unroll
    for (int m = 0; m < 2; m++)
      #pragma unroll
      for (int ks = 0; ks < 2; ks++)
        aB[m][ks] = *(const bf16x8*)(sa + (((wm*64 + (m+2)*16 + la)*128 + ks*64 + hi*16) ^ xr));

    if (t + 2 < NT) STAGE_B(ps, t + 2);

    asm volatile("s_waitcnt lgkmcnt(0)" ::: "memory");
    __builtin_amdgcn_sched_barrier(0);
    __builtin_amdgcn_s_setprio(1);
    #pragma unroll
    for (int m = 0; m < 2; m++)
      #pragma unroll
      for (int n = 0; n < 4; n++)
        #pragma unroll
        for (int ks = 0; ks < 2; ks++)
          acc[m+2][n] = __builtin_amdgcn_mfma_f32_16x16x32_bf16(aB[m][ks], bfr[n][ks], acc[m+2][n], 0, 0, 0);
    __builtin_amdgcn_s_setprio(0);

    cs = cs + 1; if (cs == 3) cs = 0;
    ps = ps + 1; if (ps == 3) ps = 0;
  }
#undef STAGE_A
#undef STAGE_B

  const int row0 = bm*128 + wm*64;
  const int col0 = bn*256 + wn*64;
  #pragma unroll
  for (int n = 0; n < 4; n++) {
    int col = col0 + n*16 + la;
    float bv = b0[col];
    #pragma unroll
    for (int m = 0; m < 4; m++)
      #pragma unroll
      for (int r = 0; r < 4; r++) {
        int row = row0 + m*16 + hi*4 + r;
        fo[(size_t)row*D_MODEL + col] = acc[m][n][r] + bv;
      }
  }
}

/* ---------------- flash attention fwd (round-10 proven: T13 defer-max +
   exp2-domain softmax) ---------------- */
__global__ __launch_bounds__(256, 2) void attn_fwd(
    const unsigned short* __restrict__ Q,
    const unsigned short* __restrict__ Kg,
    const unsigned short* __restrict__ VTg,
    unsigned short* __restrict__ O)
{
  __shared__ unsigned short Ks [2][64*128];
  __shared__ unsigned short VTs[2][128*64];

  const int tid  = threadIdx.x;
  const int lane = tid & 63, wid = tid >> 6;
  const int la   = lane & 15, hi = lane >> 4;
  const int swz  = ((int)(blockIdx.x & 7) << 6) + ((int)blockIdx.x >> 3);
  const int bh   = swz >> 4;
  const int q0   = (swz & 15) << 7;
  const int b    = bh >> 4, h = bh & 15;

  const unsigned short* Qh = Q   + (size_t)bh * SEQ * DH;
  const unsigned short* Kh = Kg  + (size_t)bh * SEQ * DH;
  const unsigned short* Vh = VTg + (size_t)bh * SEQ * DH;

  const int qrow = q0 + wid * 32;

  bf16x8 qf[2][4];
  #pragma unroll
  for (int qi = 0; qi < 2; qi++)
    #pragma unroll
    for (int ks = 0; ks < 4; ks++)
      qf[qi][ks] = *(const bf16x8*)(Qh + (size_t)(qrow + qi*16 + la)*DH + ks*32 + hi*8);

  f32x4 o[2][8];
  float mrun[2], lrun[2];
  #pragma unroll
  for (int qi = 0; qi < 2; qi++) {
    #pragma unroll
    for (int df = 0; df < 8; df++) o[qi][df] = f32x4{0.f,0.f,0.f,0.f};
    mrun[qi] = -1e30f; lrun[qi] = 0.f;
  }

  #pragma unroll
  for (int i = 0; i < 4; i++) {
    int off = i*4096 + tid*16;
    gload16((char*)Ks[0]  + off, (const char*)Kh + off);
    gload16((char*)VTs[0] + off, (const char*)Vh + off);
  }
  __syncthreads();

  /* log2-domain scale: log2(e)/sqrt(128) */
  const float sc2 = 0.1275424483f;

  #pragma unroll 1
  for (int t = 0; t < SEQ/64; ++t) {
    const int cur = t & 1;

    if (t + 1 < SEQ/64) {
      const char* kt = (const char*)(Kh + (size_t)(t+1)*(64*DH));
      const char* vt = (const char*)(Vh + (size_t)(t+1)*(64*DH));
      #pragma unroll
      for (int i = 0; i < 4; i++) {
        int off = i*4096 + tid*16;
        gload16((char*)Ks[cur^1]  + off, kt + off);
        gload16((char*)VTs[cur^1] + off, vt + off);
      }
    }

    /* S^T[kv][q] = K Q^T : S[mf][qi], kv = mf*16+hi*4+r, q = qi*16+la */
    f32x4 S[4][2];
    #pragma unroll
    for (int mf = 0; mf < 4; mf++)
      #pragma unroll
      for (int qi = 0; qi < 2; qi++) S[mf][qi] = f32x4{0.f,0.f,0.f,0.f};
    #pragma unroll
    for (int ks = 0; ks < 4; ks++) {
      bf16x8 kf[4];
      #pragma unroll
      for (int mf = 0; mf < 4; mf++) {
        int boff = (((mf*16 + la) << 8) + (ks << 6) + (hi << 4)) ^ ((la & 7) << 4);
        kf[mf] = *(const bf16x8*)((const char*)Ks[cur] + boff);
      }
      #pragma unroll
      for (int mf = 0; mf < 4; mf++)
        #pragma unroll
        for (int qi = 0; qi < 2; qi++)
          S[mf][qi] = __builtin_amdgcn_mfma_f32_16x16x32_bf16(kf[mf], qf[qi][ks], S[mf][qi], 0, 0, 0);
    }

    unsigned int pf[2][2][4];
    #pragma unroll
    for (int qi = 0; qi < 2; qi++) {
      float pm = S[0][qi][0];
      #pragma unroll
      for (int mf = 0; mf < 4; mf++)
        #pragma unroll
        for (int r = 0; r < 4; r++) pm = fmaxf(pm, S[mf][qi][r]);
      pm = fmaxf(pm, __shfl_xor(pm, 16));
      pm = fmaxf(pm, __shfl_xor(pm, 32));
      pm *= sc2;

      float mn;
      if (__all(pm <= mrun[qi] + 8.0f)) {
        mn = mrun[qi];
      } else {
        mn = fmaxf(mrun[qi], pm);
        float alpha = __builtin_amdgcn_exp2f(mrun[qi] - mn);
        mrun[qi] = mn;
        lrun[qi] *= alpha;
        #pragma unroll
        for (int r = 0; r < 4; r++) {
          float ar = __shfl(alpha, (lane & 48) | ((hi << 2) | r), 64);
          #pragma unroll
          for (int df = 0; df < 8; df++) o[qi][df][r] *= ar;
        }
      }

      float p[4][4]; float rs = 0.f;
      #pragma unroll
      for (int mf = 0; mf < 4; mf++)
        #pragma unroll
        for (int r = 0; r < 4; r++) {
          float e = __builtin_amdgcn_exp2f(fmaf(S[mf][qi][r], sc2, -mn));
          p[mf][r] = e; rs += e;
        }
      rs += __shfl_xor(rs, 16);
      rs += __shfl_xor(rs, 32);
      lrun[qi] += rs;

      unsigned int c[4][2];
      #pragma unroll
      for (int mf = 0; mf < 4; mf++) {
        c[mf][0] = cvtpk_bf16(p[mf][0], p[mf][1]);
        c[mf][1] = cvtpk_bf16(p[mf][2], p[mf][3]);
      }
      #pragma unroll
      for (int ks2 = 0; ks2 < 2; ks2++) {
        #pragma unroll
        for (int w = 0; w < 4; w++) {
          int src = la + 16*(2*(hi & 1) + (w >> 1));
          unsigned int t0 = __shfl(c[2*ks2    ][w & 1], src, 64);
          unsigned int t1 = __shfl(c[2*ks2 + 1][w & 1], src, 64);
          pf[qi][ks2][w] = (hi >> 1) ? t1 : t0;
        }
      }
    }

    #pragma unroll
    for (int ks2 = 0; ks2 < 2; ks2++) {
      #pragma unroll
      for (int df = 0; df < 8; df++) {
        int vrow = df*16 + la;
        int boff = ((vrow << 7) + (ks2 << 6) + (hi << 4)) ^ ((la & 7) << 4);
        bf16x8 vf = *(const bf16x8*)((const char*)VTs[cur] + boff);
        #pragma unroll
        for (int qi = 0; qi < 2; qi++) {
          u32x4 pw = {pf[qi][ks2][0], pf[qi][ks2][1], pf[qi][ks2][2], pf[qi][ks2][3]};
          o[qi][df] = __builtin_amdgcn_mfma_f32_16x16x32_bf16(
              __builtin_bit_cast(bf16x8, pw), vf, o[qi][df], 0, 0, 0);
        }
      }
    }
    __syncthreads();
  }

  unsigned short* Ob = O + (size_t)b * SEQ * D_MODEL + h * DH;
  #pragma unroll
  for (int qi = 0; qi < 2; qi++) {
    float linv[4];
    #pragma unroll
    for (int r = 0; r < 4; r++)
      linv[r] = 1.0f / __shfl(lrun[qi], (lane & 48) | ((hi << 2) | r), 64);
    #pragma unroll
    for (int df = 0; df < 8; df++)
      #pragma unroll
      for (int r = 0; r < 4; r++) {
        int srow = qrow + qi*16 + hi*4 + r;
        Ob[(size_t)srow * D_MODEL + df*16 + la] = f2bf(o[qi][df][r] * linv[r]);
      }
  }
}

/* ---------------- launcher ---------------- */
extern "C" void kernel_launch(void* const* d_in, const int* in_sizes, int n_in,
                              void* d_out, int out_size, void* d_ws, size_t ws_size,
                              hipStream_t stream) {
  const float* x  = (const float*)d_in[0];
  const float* wq = (const float*)d_in[1];
  const float* bq = (const float*)d_in[2];
  const float* wk = (const float*)d_in[3];
  const float* bk = (const float*)d_in[4];
  const float* wv = (const float*)d_in[5];
  const float* bv = (const float*)d_in[6];
  const float* wo = (const float*)d_in[7];
  const float* bo = (const float*)d_in[8];
  float* out = (float*)d_out;

  const size_t X = (size_t)MROWS * D_MODEL;   /* 8388608  */
  const size_t W = (size_t)D_MODEL * D_MODEL; /* 4194304  */

  unsigned short* ws  = (unsigned short*)d_ws;
  unsigned short* xb  = ws;
  unsigned short* wqb = xb  + X;   /* wqb,wkb,wvb,wob contiguous */
  unsigned short* wkb = wqb + W;
  unsigned short* wvb = wkb + W;
  unsigned short* wob = wvb + W;
  unsigned short* qb  = wob + W;
  unsigned short* kb  = qb  + X;
  unsigned short* vtg = kb  + X;
  unsigned short* ab  = vtg + X;

  cast_all<<<dim3(12288), 256, 0, stream>>>(x, wq, wk, wv, wo, xb, wqb);

  /* fused QKV: M=4096, N=6144, 256x192 tiles -> 16x32 = 512 blocks
     (2 exact CU-rounds at 1 block/CU) */
  gemm192<<<dim3(512), 512, 0, stream>>>(xb, wqb, bq, bk, bv, qb, kb, vtg);

  attn_fwd<<<dim3(512), 256, 0, stream>>>(qb, kb, vtg, ab);

  /* out-proj: M=4096, N=2048 -> 32x8 = 256 blocks (1 exact CU-round) */
  gemm256<<<dim3(256), 512, 0, stream>>>(ab, wob, bo, out, 1);
}